// Round 2
// baseline (762.408 us; speedup 1.0000x reference)
//
#include <hip/hip_runtime.h>
#include <hip/hip_bf16.h>
#include <cstdint>
#include <cstddef>

// Problem constants (from reference)
#define NNODES 50000
#define NEDGES 800000
// IN_F=256, HID_F=128, OUT_F=64

typedef unsigned short u16;
typedef short bfrag8 __attribute__((ext_vector_type(8)));
typedef float f32x4 __attribute__((ext_vector_type(4)));

__device__ __forceinline__ u16 f2bf(float f) {
    union { float f; uint32_t i; } v; v.f = f;
    uint32_t r = (v.i + 0x7FFFu + ((v.i >> 16) & 1u)) >> 16;
    return (u16)r;
}

// ---- degree histogram ----
__global__ __launch_bounds__(256) void deg_kernel(const int* __restrict__ src, const int* __restrict__ dst,
                                                  int* __restrict__ cout_, int* __restrict__ cin_, int nE) {
    int i = blockIdx.x * 256 + threadIdx.x;
    if (i < nE) {
        atomicAdd(&cout_[src[i]], 1);
        atomicAdd(&cin_[dst[i]], 1);
    }
}

// ---- rsqrt(clip(deg,1)) ----
__global__ __launch_bounds__(256) void rs_kernel(const int* __restrict__ cout_, const int* __restrict__ cin_,
                                                 float* __restrict__ rout, float* __restrict__ rin, int n) {
    int i = blockIdx.x * 256 + threadIdx.x;
    if (i < n) {
        int co = cout_[i]; if (co < 1) co = 1;
        int ci = cin_[i];  if (ci < 1) ci = 1;
        rout[i] = rsqrtf((float)co);
        rin[i]  = rsqrtf((float)ci);
    }
}

// ---- MFMA GEMM: out[M,N] = (A[M,K] @ W[K,N]) * rs[row]  (fp32 in/out, bf16 MFMA inside) ----
// Block: 256 threads = 4 waves; each wave computes a 16-row x N strip; block covers 64 rows.
// W (fp32) is converted to bf16 and staged to LDS in swizzled layout Wl[k/8][n][k%8]
// so each lane's B-frag is one ds_read_b128.
// AF32: A is fp32 (convert inline); else A is bf16 (u16).
template <int K, int N, bool AF32>
__global__ __launch_bounds__(256) void gemm_scaled(const void* __restrict__ A_, const float* __restrict__ W,
                                                   const float* __restrict__ rs, float* __restrict__ out, int M) {
    __shared__ __align__(16) u16 Wl[K * N];
    constexpr int NO4 = N / 4;
    // stage W: coalesced fp32 global reads (4 contiguous n per thread), cvt to bf16, scattered LDS writes
    for (int idx = threadIdx.x; idx < K * NO4; idx += 256) {
        int k = idx / NO4;
        int n0 = (idx - k * NO4) * 4;
        const float4 w = *(const float4*)(W + k * N + n0);
        int base = (k >> 3) * (N * 8) + (k & 7);
        Wl[base + (n0 + 0) * 8] = f2bf(w.x);
        Wl[base + (n0 + 1) * 8] = f2bf(w.y);
        Wl[base + (n0 + 2) * 8] = f2bf(w.z);
        Wl[base + (n0 + 3) * 8] = f2bf(w.w);
    }
    __syncthreads();

    const int lane = threadIdx.x & 63;
    const int wave = threadIdx.x >> 6;
    const int m = lane & 15;      // A row within tile / D col within tile
    const int q = lane >> 4;      // k-quad
    const int row0 = blockIdx.x * 64 + wave * 16;

    int rowa = row0 + m; if (rowa > M - 1) rowa = M - 1;   // clamp OOB loads

    constexpr int NT = N / 16;
    f32x4 acc[NT];
    #pragma unroll
    for (int t = 0; t < NT; t++) acc[t] = (f32x4){0.f, 0.f, 0.f, 0.f};

    for (int kc = 0; kc < K; kc += 32) {
        bfrag8 af;
        if constexpr (AF32) {
            const float* ap = (const float*)A_ + (size_t)rowa * K + q * 8 + kc;
            const float4 x0 = *(const float4*)(ap);
            const float4 x1 = *(const float4*)(ap + 4);
            af[0] = (short)f2bf(x0.x); af[1] = (short)f2bf(x0.y);
            af[2] = (short)f2bf(x0.z); af[3] = (short)f2bf(x0.w);
            af[4] = (short)f2bf(x1.x); af[5] = (short)f2bf(x1.y);
            af[6] = (short)f2bf(x1.z); af[7] = (short)f2bf(x1.w);
        } else {
            const u16* ap = (const u16*)A_ + (size_t)rowa * K + q * 8 + kc;
            af = *(const bfrag8*)ap;
        }
        const u16* bbase = &Wl[((kc >> 3) + q) * (N * 8) + m * 8];
        #pragma unroll
        for (int t = 0; t < NT; t++) {
            bfrag8 bf_ = *(const bfrag8*)(bbase + t * 128);
            acc[t] = __builtin_amdgcn_mfma_f32_16x16x32_bf16(af, bf_, acc[t], 0, 0, 0);
        }
    }
    // C/D layout (gfx950, m89-verified): col = lane&15, row = (lane>>4)*4 + r
    #pragma unroll
    for (int r = 0; r < 4; r++) {
        int gr = row0 + q * 4 + r;
        if (gr < M) {
            float s = rs[gr];
            #pragma unroll
            for (int t = 0; t < NT; t++)
                out[(size_t)gr * N + t * 16 + m] = acc[t][r] * s;
        }
    }
}

// ---- edge scatter: agg[dst,:] += h[src,:]  (fp32 atomics) ----
template <int F>
__global__ __launch_bounds__(256) void scatter_add(const float* __restrict__ h, const int* __restrict__ src,
                                                   const int* __restrict__ dst, float* __restrict__ agg, int nE) {
    constexpr int EPB = 256 / F;
    int e = blockIdx.x * EPB + threadIdx.x / F;
    if (e >= nE) return;
    int f = threadIdx.x & (F - 1);
    int s = src[e], d = dst[e];
    atomicAdd(&agg[(size_t)d * F + f], h[(size_t)s * F + f]);
}

// ---- layer-1 epilogue: h1 = relu(agg*rs_in + b1), bf16 out (feeds GEMM2's A) ----
__global__ __launch_bounds__(256) void epi1(const float* __restrict__ agg, const float* __restrict__ rin,
                                            const float* __restrict__ b1, u16* __restrict__ h1, int n) {
    int i = blockIdx.x * 256 + threadIdx.x;
    if (i >= n) return;
    int node = i >> 7;        // /128
    int f = i & 127;
    float v = agg[i] * rin[node] + b1[f];
    h1[i] = f2bf(fmaxf(v, 0.f));
}

// ---- layer-2 epilogue + final projection: wave per node (fp32 outputs) ----
__global__ __launch_bounds__(256) void epi2(const float* __restrict__ agg2, const float* __restrict__ rin,
                                            const float* __restrict__ b2, const float* __restrict__ Wf,
                                            const float* __restrict__ bfv,
                                            float* __restrict__ logits, float* __restrict__ hidden, int nNodes) {
    int lane = threadIdx.x & 63;
    int node = blockIdx.x * 4 + (threadIdx.x >> 6);
    if (node >= nNodes) return;
    float v = agg2[(size_t)node * 64 + lane] * rin[node] + b2[lane];
    hidden[(size_t)node * 64 + lane] = v;
    float l0 = v * Wf[lane * 2 + 0];
    float l1 = v * Wf[lane * 2 + 1];
    #pragma unroll
    for (int off = 32; off > 0; off >>= 1) {
        l0 += __shfl_down(l0, off, 64);
        l1 += __shfl_down(l1, off, 64);
    }
    if (lane == 0) {
        logits[(size_t)node * 2 + 0] = l0 + bfv[0];
        logits[(size_t)node * 2 + 1] = l1 + bfv[1];
    }
}

extern "C" void kernel_launch(void* const* d_in, const int* in_sizes, int n_in,
                              void* d_out, int out_size, void* d_ws, size_t ws_size,
                              hipStream_t stream) {
    const float* x   = (const float*)d_in[0];   // [50000,256] fp32
    const float* W1  = (const float*)d_in[1];   // [256,128]
    const float* b1  = (const float*)d_in[2];   // [128]
    const float* W2  = (const float*)d_in[3];   // [128,64]
    const float* b2  = (const float*)d_in[4];   // [64]
    const float* Wf  = (const float*)d_in[5];   // [64,2]
    const float* bfv = (const float*)d_in[6];   // [2]
    const int* src = (const int*)d_in[7];   // [800000]
    const int* dst = (const int*)d_in[8];   // [800000]

    float* out_logits = (float*)d_out;                 // [50000,2]
    float* out_hidden = (float*)d_out + 2 * NNODES;    // [50000,64]

    // workspace carve-up (256B-aligned chunks); total ~64.8 MB
    char* ws = (char*)d_ws;
    size_t off = 0;
    auto alloc = [&](size_t bytes) { void* p = ws + off; off += (bytes + 255) & ~(size_t)255; return p; };
    int*   cnt_out = (int*)alloc(NNODES * 4);
    int*   cnt_in  = (int*)alloc(NNODES * 4);
    float* rs_o    = (float*)alloc(NNODES * 4);
    float* rs_i    = (float*)alloc(NNODES * 4);
    float* h       = (float*)alloc((size_t)NNODES * 128 * 4);   // layer1 transform (reused as h2)
    float* agg1    = (float*)alloc((size_t)NNODES * 128 * 4);   // layer1 aggregate (reused as agg2)
    u16*   h1      = (u16*)alloc((size_t)NNODES * 128 * 2);     // relu'd hidden, bf16 (GEMM2 input)
    float* h2   = h;     // [50000,64] fp32, fits in h region
    float* agg2 = agg1;  // [50000,64] fp32, fits in agg1 region

    // zero-init (ws is poisoned 0xAA before every call)
    hipMemsetAsync(cnt_out, 0, NNODES * 4, stream);
    hipMemsetAsync(cnt_in,  0, NNODES * 4, stream);
    hipMemsetAsync(agg1,    0, (size_t)NNODES * 128 * 4, stream);

    deg_kernel<<<(NEDGES + 255) / 256, 256, 0, stream>>>(src, dst, cnt_out, cnt_in, NEDGES);
    rs_kernel<<<(NNODES + 255) / 256, 256, 0, stream>>>(cnt_out, cnt_in, rs_o, rs_i, NNODES);

    // layer 1: h = (x @ W1) * rsqrt(deg_out)
    gemm_scaled<256, 128, true><<<(NNODES + 63) / 64, 256, 0, stream>>>(x, W1, rs_o, h, NNODES);
    scatter_add<128><<<NEDGES / 2, 256, 0, stream>>>(h, src, dst, agg1, NEDGES);
    epi1<<<(NNODES * 128 + 255) / 256, 256, 0, stream>>>(agg1, rs_i, b1, h1, NNODES * 128);

    // layer 2: h2 = (h1 @ W2) * rsqrt(deg_out)   (agg2 zeroed after epi1 consumed agg1)
    hipMemsetAsync(agg2, 0, (size_t)NNODES * 64 * 4, stream);
    gemm_scaled<128, 64, false><<<(NNODES + 63) / 64, 256, 0, stream>>>(h1, W2, rs_o, h2, NNODES);
    scatter_add<64><<<NEDGES / 4, 256, 0, stream>>>(h2, src, dst, agg2, NEDGES);

    // hidden = agg2*rs_in + b2 ; logits = hidden @ Wf + bf
    epi2<<<(NNODES + 3) / 4, 256, 0, stream>>>(agg2, rs_i, b2, Wf, bfv, out_logits, out_hidden, NNODES);
}

// Round 3
// 355.451 us; speedup vs baseline: 2.1449x; 2.1449x over previous
//
#include <hip/hip_runtime.h>
#include <hip/hip_bf16.h>
#include <cstdint>
#include <cstddef>

#define NNODES 50000
#define NEDGES 800000
#define NBLK   ((NNODES + 255) / 256)   // 196 scan blocks

typedef unsigned short u16;
typedef unsigned int u32;
typedef short bfrag8 __attribute__((ext_vector_type(8)));
typedef float f32x4 __attribute__((ext_vector_type(4)));

__device__ __forceinline__ u16 f2bf(float f) {
    union { float f; uint32_t i; } v; v.f = f;
    uint32_t r = (v.i + 0x7FFFu + ((v.i >> 16) & 1u)) >> 16;
    return (u16)r;
}
__device__ __forceinline__ float bflo(u32 p) { union { uint32_t i; float f; } v; v.i = p << 16; return v.f; }
__device__ __forceinline__ float bfhi(u32 p) { union { uint32_t i; float f; } v; v.i = p & 0xFFFF0000u; return v.f; }

// ---- degree histogram (int atomics) ----
__global__ __launch_bounds__(256) void deg_kernel(const int* __restrict__ src, const int* __restrict__ dst,
                                                  int* __restrict__ cout_, int* __restrict__ cin_, int nE) {
    int i = blockIdx.x * 256 + threadIdx.x;
    if (i < nE) {
        atomicAdd(&cout_[src[i]], 1);
        atomicAdd(&cin_[dst[i]], 1);
    }
}

// ---- rsqrt(clip(deg,1)) ----
__global__ __launch_bounds__(256) void rs_kernel(const int* __restrict__ cout_, const int* __restrict__ cin_,
                                                 float* __restrict__ rout, float* __restrict__ rin, int n) {
    int i = blockIdx.x * 256 + threadIdx.x;
    if (i < n) {
        int co = cout_[i]; if (co < 1) co = 1;
        int ci = cin_[i];  if (ci < 1) ci = 1;
        rout[i] = rsqrtf((float)co);
        rin[i]  = rsqrtf((float)ci);
    }
}

// ---- scan step 1: per-block inclusive scan of cnt_in + block totals ----
__global__ __launch_bounds__(256) void scan_partial(const int* __restrict__ cnt, int* __restrict__ scanned,
                                                    int* __restrict__ partials, int n) {
    __shared__ int sd[256];
    int t = threadIdx.x;
    int i = blockIdx.x * 256 + t;
    int v = (i < n) ? cnt[i] : 0;
    sd[t] = v;
    __syncthreads();
    #pragma unroll
    for (int o = 1; o < 256; o <<= 1) {
        int add = (t >= o) ? sd[t - o] : 0;
        __syncthreads();
        sd[t] += add;
        __syncthreads();
    }
    if (i < n) scanned[i] = sd[t];
    if (t == 255) partials[blockIdx.x] = sd[255];
}

// ---- scan step 2: exclusive scan of block totals (single block) ----
__global__ __launch_bounds__(256) void scan_offs(const int* __restrict__ partials, int* __restrict__ offs, int nb) {
    __shared__ int sd[256];
    int t = threadIdx.x;
    int v = (t < nb) ? partials[t] : 0;
    sd[t] = v;
    __syncthreads();
    #pragma unroll
    for (int o = 1; o < 256; o <<= 1) {
        int add = (t >= o) ? sd[t - o] : 0;
        __syncthreads();
        sd[t] += add;
        __syncthreads();
    }
    if (t < nb) offs[t] = sd[t] - v;   // exclusive
}

// ---- scan step 3: row_ptr + write cursor ----
__global__ __launch_bounds__(256) void scan_final(const int* __restrict__ scanned, const int* __restrict__ offs,
                                                  const int* __restrict__ cnt, int* __restrict__ row_ptr,
                                                  int* __restrict__ cursor, int n) {
    int i = blockIdx.x * 256 + threadIdx.x;
    if (i < n) {
        int incl = scanned[i] + offs[blockIdx.x];
        row_ptr[i + 1] = incl;
        cursor[i] = incl - cnt[i];
        if (i == 0) row_ptr[0] = 0;
    }
}

// ---- CSR build: bucket src ids by dst ----
__global__ __launch_bounds__(256) void csr_build(const int* __restrict__ src, const int* __restrict__ dst,
                                                 int* __restrict__ cursor, int* __restrict__ col_idx, int nE) {
    int e = blockIdx.x * 256 + threadIdx.x;
    if (e < nE) {
        int pos = atomicAdd(&cursor[dst[e]], 1);
        col_idx[pos] = src[e];
    }
}

// ---- MFMA GEMM: out_bf16[M,N] = bf16round((A[M,K] @ W[K,N]) * rs[row]) ----
// 4 waves/block, wave = 16-row strip, block = 64 rows. W staged to LDS swizzled
// Wl[k/8][n][k%8] so each lane's B-frag is one ds_read_b128.
template <int K, int N, bool AF32>
__global__ __launch_bounds__(256) void gemm_scaled(const void* __restrict__ A_, const float* __restrict__ W,
                                                   const float* __restrict__ rs, u16* __restrict__ out, int M) {
    __shared__ __align__(16) u16 Wl[K * N];
    constexpr int NO4 = N / 4;
    for (int idx = threadIdx.x; idx < K * NO4; idx += 256) {
        int k = idx / NO4;
        int n0 = (idx - k * NO4) * 4;
        const float4 w = *(const float4*)(W + k * N + n0);
        int base = (k >> 3) * (N * 8) + (k & 7);
        Wl[base + (n0 + 0) * 8] = f2bf(w.x);
        Wl[base + (n0 + 1) * 8] = f2bf(w.y);
        Wl[base + (n0 + 2) * 8] = f2bf(w.z);
        Wl[base + (n0 + 3) * 8] = f2bf(w.w);
    }
    __syncthreads();

    const int lane = threadIdx.x & 63;
    const int wave = threadIdx.x >> 6;
    const int m = lane & 15;
    const int q = lane >> 4;
    const int row0 = blockIdx.x * 64 + wave * 16;

    int rowa = row0 + m; if (rowa > M - 1) rowa = M - 1;

    constexpr int NT = N / 16;
    f32x4 acc[NT];
    #pragma unroll
    for (int t = 0; t < NT; t++) acc[t] = (f32x4){0.f, 0.f, 0.f, 0.f};

    for (int kc = 0; kc < K; kc += 32) {
        bfrag8 af;
        if constexpr (AF32) {
            const float* ap = (const float*)A_ + (size_t)rowa * K + q * 8 + kc;
            const float4 x0 = *(const float4*)(ap);
            const float4 x1 = *(const float4*)(ap + 4);
            af[0] = (short)f2bf(x0.x); af[1] = (short)f2bf(x0.y);
            af[2] = (short)f2bf(x0.z); af[3] = (short)f2bf(x0.w);
            af[4] = (short)f2bf(x1.x); af[5] = (short)f2bf(x1.y);
            af[6] = (short)f2bf(x1.z); af[7] = (short)f2bf(x1.w);
        } else {
            const u16* ap = (const u16*)A_ + (size_t)rowa * K + q * 8 + kc;
            af = *(const bfrag8*)ap;
        }
        const u16* bbase = &Wl[((kc >> 3) + q) * (N * 8) + m * 8];
        #pragma unroll
        for (int t = 0; t < NT; t++) {
            bfrag8 bf_ = *(const bfrag8*)(bbase + t * 128);
            acc[t] = __builtin_amdgcn_mfma_f32_16x16x32_bf16(af, bf_, acc[t], 0, 0, 0);
        }
    }
    // C/D: col = lane&15, row = (lane>>4)*4 + r
    #pragma unroll
    for (int r = 0; r < 4; r++) {
        int gr = row0 + q * 4 + r;
        if (gr < M) {
            float s = rs[gr];
            #pragma unroll
            for (int t = 0; t < NT; t++)
                out[(size_t)gr * N + t * 16 + m] = f2bf(acc[t][r] * s);
        }
    }
}

// ---- layer-1 gather + epilogue: h1[n,:] = relu(rin[n] * sum_{e in row(n)} h[col[e],:] + b1) ----
// F=128 as 64 lanes x 2 bf16 features; one wave per node; 4 nodes/block.
__global__ __launch_bounds__(256) void gather1(const u32* __restrict__ h,       // [NNODES,64] bf16x2
                                               const int* __restrict__ row_ptr, const int* __restrict__ col_idx,
                                               const float* __restrict__ rin, const float* __restrict__ b1,
                                               u32* __restrict__ h1out, int nNodes) {
    int lane = threadIdx.x & 63;
    int node = blockIdx.x * 4 + (threadIdx.x >> 6);
    if (node >= nNodes) return;
    int beg = row_ptr[node], end = row_ptr[node + 1];
    float a0 = 0.f, a1 = 0.f;
    int e = beg;
    for (; e + 1 < end; e += 2) {
        int s0 = col_idx[e], s1 = col_idx[e + 1];
        u32 p0 = h[(size_t)s0 * 64 + lane];
        u32 p1 = h[(size_t)s1 * 64 + lane];
        a0 += bflo(p0) + bflo(p1);
        a1 += bfhi(p0) + bfhi(p1);
    }
    if (e < end) {
        u32 p = h[(size_t)col_idx[e] * 64 + lane];
        a0 += bflo(p);
        a1 += bfhi(p);
    }
    float r = rin[node];
    float v0 = fmaxf(a0 * r + b1[2 * lane + 0], 0.f);
    float v1 = fmaxf(a1 * r + b1[2 * lane + 1], 0.f);
    h1out[(size_t)node * 64 + lane] = ((u32)f2bf(v1) << 16) | f2bf(v0);
}

// ---- layer-2 gather + epilogue + final projection ----
// F=64 as 32 lanes x 2 bf16 features; half-wave per node; 8 nodes/block.
__global__ __launch_bounds__(256) void gather2(const u32* __restrict__ h2,      // [NNODES,32] bf16x2
                                               const int* __restrict__ row_ptr, const int* __restrict__ col_idx,
                                               const float* __restrict__ rin, const float* __restrict__ b2,
                                               const float* __restrict__ Wf, const float* __restrict__ bfv,
                                               float* __restrict__ logits, float* __restrict__ hidden, int nNodes) {
    int lane = threadIdx.x & 63;
    int l = lane & 31;
    int node = blockIdx.x * 8 + (threadIdx.x >> 5);
    if (node >= nNodes) return;
    int beg = row_ptr[node], end = row_ptr[node + 1];
    float a0 = 0.f, a1 = 0.f;
    int e = beg;
    for (; e + 1 < end; e += 2) {
        int s0 = col_idx[e], s1 = col_idx[e + 1];
        u32 p0 = h2[(size_t)s0 * 32 + l];
        u32 p1 = h2[(size_t)s1 * 32 + l];
        a0 += bflo(p0) + bflo(p1);
        a1 += bfhi(p0) + bfhi(p1);
    }
    if (e < end) {
        u32 p = h2[(size_t)col_idx[e] * 32 + l];
        a0 += bflo(p);
        a1 += bfhi(p);
    }
    float r = rin[node];
    float v0 = a0 * r + b2[2 * l + 0];
    float v1 = a1 * r + b2[2 * l + 1];
    hidden[(size_t)node * 64 + 2 * l + 0] = v0;
    hidden[(size_t)node * 64 + 2 * l + 1] = v1;
    float l0 = v0 * Wf[(2 * l) * 2 + 0] + v1 * Wf[(2 * l + 1) * 2 + 0];
    float l1 = v0 * Wf[(2 * l) * 2 + 1] + v1 * Wf[(2 * l + 1) * 2 + 1];
    #pragma unroll
    for (int off = 16; off > 0; off >>= 1) {
        l0 += __shfl_down(l0, off, 32);
        l1 += __shfl_down(l1, off, 32);
    }
    if (l == 0) {
        logits[(size_t)node * 2 + 0] = l0 + bfv[0];
        logits[(size_t)node * 2 + 1] = l1 + bfv[1];
    }
}

extern "C" void kernel_launch(void* const* d_in, const int* in_sizes, int n_in,
                              void* d_out, int out_size, void* d_ws, size_t ws_size,
                              hipStream_t stream) {
    const float* x   = (const float*)d_in[0];
    const float* W1  = (const float*)d_in[1];
    const float* b1  = (const float*)d_in[2];
    const float* W2  = (const float*)d_in[3];
    const float* b2  = (const float*)d_in[4];
    const float* Wf  = (const float*)d_in[5];
    const float* bfv = (const float*)d_in[6];
    const int* src = (const int*)d_in[7];
    const int* dst = (const int*)d_in[8];

    float* out_logits = (float*)d_out;
    float* out_hidden = (float*)d_out + 2 * NNODES;

    char* ws = (char*)d_ws;
    size_t off = 0;
    auto alloc = [&](size_t bytes) { void* p = ws + off; off += (bytes + 255) & ~(size_t)255; return p; };
    int*   cnt_out = (int*)alloc(NNODES * 4);
    int*   cnt_in  = (int*)alloc(NNODES * 4);
    float* rs_o    = (float*)alloc(NNODES * 4);
    float* rs_i    = (float*)alloc(NNODES * 4);
    int*   scanned = (int*)alloc(NNODES * 4);
    int*   partials= (int*)alloc(256 * 4);
    int*   offs    = (int*)alloc(256 * 4);
    int*   row_ptr = (int*)alloc((NNODES + 1) * 4);
    int*   cursor  = (int*)alloc(NNODES * 4);
    int*   col_idx = (int*)alloc((size_t)NEDGES * 4);
    u16*   h       = (u16*)alloc((size_t)NNODES * 128 * 2);   // layer1 transform, bf16 scaled
    u16*   h1      = (u16*)alloc((size_t)NNODES * 128 * 2);   // relu'd hidden, bf16
    u16*   h2      = (u16*)alloc((size_t)NNODES * 64 * 2);    // layer2 transform, bf16 scaled

    hipMemsetAsync(cnt_out, 0, NNODES * 4, stream);
    hipMemsetAsync(cnt_in,  0, NNODES * 4, stream);

    deg_kernel<<<(NEDGES + 255) / 256, 256, 0, stream>>>(src, dst, cnt_out, cnt_in, NEDGES);
    rs_kernel<<<NBLK, 256, 0, stream>>>(cnt_out, cnt_in, rs_o, rs_i, NNODES);

    // CSR by dst
    scan_partial<<<NBLK, 256, 0, stream>>>(cnt_in, scanned, partials, NNODES);
    scan_offs<<<1, 256, 0, stream>>>(partials, offs, NBLK);
    scan_final<<<NBLK, 256, 0, stream>>>(scanned, offs, cnt_in, row_ptr, cursor, NNODES);
    csr_build<<<(NEDGES + 255) / 256, 256, 0, stream>>>(src, dst, cursor, col_idx, NEDGES);

    // layer 1
    gemm_scaled<256, 128, true><<<(NNODES + 63) / 64, 256, 0, stream>>>(x, W1, rs_o, h, NNODES);
    gather1<<<(NNODES + 3) / 4, 256, 0, stream>>>((const u32*)h, row_ptr, col_idx, rs_i, b1, (u32*)h1, NNODES);

    // layer 2
    gemm_scaled<128, 64, false><<<(NNODES + 63) / 64, 256, 0, stream>>>(h1, W2, rs_o, h2, NNODES);
    gather2<<<(NNODES + 7) / 8, 256, 0, stream>>>((const u32*)h2, row_ptr, col_idx, rs_i, b2, Wf, bfv,
                                                  out_logits, out_hidden, NNODES);
}

// Round 4
// 321.722 us; speedup vs baseline: 2.3698x; 1.1048x over previous
//
#include <hip/hip_runtime.h>
#include <hip/hip_bf16.h>
#include <cstdint>
#include <cstddef>

#define NNODES 50000
#define NEDGES 800000
#define NBLK   ((NNODES + 255) / 256)   // 196 scan blocks

typedef unsigned short u16;
typedef unsigned int u32;
typedef short bfrag8 __attribute__((ext_vector_type(8)));
typedef float f32x4 __attribute__((ext_vector_type(4)));

__device__ __forceinline__ u16 f2bf(float f) {
    union { float f; uint32_t i; } v; v.f = f;
    uint32_t r = (v.i + 0x7FFFu + ((v.i >> 16) & 1u)) >> 16;
    return (u16)r;
}
__device__ __forceinline__ float bflo(u32 p) { union { uint32_t i; float f; } v; v.i = p << 16; return v.f; }
__device__ __forceinline__ float bfhi(u32 p) { union { uint32_t i; float f; } v; v.i = p & 0xFFFF0000u; return v.f; }

// ---- degree histogram + in-bucket rank (atomic does double duty) ----
__global__ __launch_bounds__(256) void deg_rank_kernel(const int* __restrict__ src, const int* __restrict__ dst,
                                                       int* __restrict__ cout_, int* __restrict__ cin_,
                                                       int* __restrict__ rank, int nE) {
    int i = blockIdx.x * 256 + threadIdx.x;
    if (i < nE) {
        atomicAdd(&cout_[src[i]], 1);                 // fire-and-forget
        rank[i] = atomicAdd(&cin_[dst[i]], 1);        // count + rank in one op
    }
}

// ---- scan step 1: per-block inclusive scan of cnt_in + block totals ----
__global__ __launch_bounds__(256) void scan_partial(const int* __restrict__ cnt, int* __restrict__ scanned,
                                                    int* __restrict__ partials, int n) {
    __shared__ int sd[256];
    int t = threadIdx.x;
    int i = blockIdx.x * 256 + t;
    int v = (i < n) ? cnt[i] : 0;
    sd[t] = v;
    __syncthreads();
    #pragma unroll
    for (int o = 1; o < 256; o <<= 1) {
        int add = (t >= o) ? sd[t - o] : 0;
        __syncthreads();
        sd[t] += add;
        __syncthreads();
    }
    if (i < n) scanned[i] = sd[t];
    if (t == 255) partials[blockIdx.x] = sd[255];
}

// ---- scan step 2: exclusive scan of block totals (single block) ----
__global__ __launch_bounds__(256) void scan_offs(const int* __restrict__ partials, int* __restrict__ offs, int nb) {
    __shared__ int sd[256];
    int t = threadIdx.x;
    int v = (t < nb) ? partials[t] : 0;
    sd[t] = v;
    __syncthreads();
    #pragma unroll
    for (int o = 1; o < 256; o <<= 1) {
        int add = (t >= o) ? sd[t - o] : 0;
        __syncthreads();
        sd[t] += add;
        __syncthreads();
    }
    if (t < nb) offs[t] = sd[t] - v;   // exclusive
}

// ---- scan step 3: row_ptr + rsqrt norms (rs fused here) ----
__global__ __launch_bounds__(256) void scan_final_rs(const int* __restrict__ scanned, const int* __restrict__ offs,
                                                     const int* __restrict__ cnt_in, const int* __restrict__ cnt_out,
                                                     int* __restrict__ row_ptr,
                                                     float* __restrict__ rs_o, float* __restrict__ rs_i, int n) {
    int i = blockIdx.x * 256 + threadIdx.x;
    if (i < n) {
        int incl = scanned[i] + offs[blockIdx.x];
        row_ptr[i + 1] = incl;
        if (i == 0) row_ptr[0] = 0;
        int co = cnt_out[i]; if (co < 1) co = 1;
        int ci = cnt_in[i];  if (ci < 1) ci = 1;
        rs_o[i] = rsqrtf((float)co);
        rs_i[i] = rsqrtf((float)ci);
    }
}

// ---- CSR placement: deterministic, no atomics ----
__global__ __launch_bounds__(256) void csr_place(const int* __restrict__ src, const int* __restrict__ dst,
                                                 const int* __restrict__ rank, const int* __restrict__ row_ptr,
                                                 int* __restrict__ col_idx, int nE) {
    int e = blockIdx.x * 256 + threadIdx.x;
    if (e < nE) {
        col_idx[row_ptr[dst[e]] + rank[e]] = src[e];
    }
}

// ---- MFMA GEMM: out_bf16[M,N] = bf16round((A[M,K] @ W[K,N]) * rs[row]) ----
// 4 waves/block, wave = 16-row strip, block = 64 rows. W staged to LDS swizzled
// Wl[k/8][n][k%8] so each lane's B-frag is one ds_read_b128.
template <int K, int N, bool AF32>
__global__ __launch_bounds__(256) void gemm_scaled(const void* __restrict__ A_, const float* __restrict__ W,
                                                   const float* __restrict__ rs, u16* __restrict__ out, int M) {
    __shared__ __align__(16) u16 Wl[K * N];
    constexpr int NO4 = N / 4;
    for (int idx = threadIdx.x; idx < K * NO4; idx += 256) {
        int k = idx / NO4;
        int n0 = (idx - k * NO4) * 4;
        const float4 w = *(const float4*)(W + k * N + n0);
        int base = (k >> 3) * (N * 8) + (k & 7);
        Wl[base + (n0 + 0) * 8] = f2bf(w.x);
        Wl[base + (n0 + 1) * 8] = f2bf(w.y);
        Wl[base + (n0 + 2) * 8] = f2bf(w.z);
        Wl[base + (n0 + 3) * 8] = f2bf(w.w);
    }
    __syncthreads();

    const int lane = threadIdx.x & 63;
    const int wave = threadIdx.x >> 6;
    const int m = lane & 15;
    const int q = lane >> 4;
    const int row0 = blockIdx.x * 64 + wave * 16;

    int rowa = row0 + m; if (rowa > M - 1) rowa = M - 1;

    constexpr int NT = N / 16;
    f32x4 acc[NT];
    #pragma unroll
    for (int t = 0; t < NT; t++) acc[t] = (f32x4){0.f, 0.f, 0.f, 0.f};

    for (int kc = 0; kc < K; kc += 32) {
        bfrag8 af;
        if constexpr (AF32) {
            const float* ap = (const float*)A_ + (size_t)rowa * K + q * 8 + kc;
            const float4 x0 = *(const float4*)(ap);
            const float4 x1 = *(const float4*)(ap + 4);
            af[0] = (short)f2bf(x0.x); af[1] = (short)f2bf(x0.y);
            af[2] = (short)f2bf(x0.z); af[3] = (short)f2bf(x0.w);
            af[4] = (short)f2bf(x1.x); af[5] = (short)f2bf(x1.y);
            af[6] = (short)f2bf(x1.z); af[7] = (short)f2bf(x1.w);
        } else {
            const u16* ap = (const u16*)A_ + (size_t)rowa * K + q * 8 + kc;
            af = *(const bfrag8*)ap;
        }
        const u16* bbase = &Wl[((kc >> 3) + q) * (N * 8) + m * 8];
        #pragma unroll
        for (int t = 0; t < NT; t++) {
            bfrag8 bf_ = *(const bfrag8*)(bbase + t * 128);
            acc[t] = __builtin_amdgcn_mfma_f32_16x16x32_bf16(af, bf_, acc[t], 0, 0, 0);
        }
    }
    // C/D: col = lane&15, row = (lane>>4)*4 + r
    #pragma unroll
    for (int r = 0; r < 4; r++) {
        int gr = row0 + q * 4 + r;
        if (gr < M) {
            float s = rs[gr];
            #pragma unroll
            for (int t = 0; t < NT; t++)
                out[(size_t)gr * N + t * 16 + m] = f2bf(acc[t][r] * s);
        }
    }
}

// ---- layer-1 gather + epilogue: h1[n,:] = relu(rin[n] * sum_{e in row(n)} h[col[e],:] + b1) ----
// F=128 as 64 lanes x 2 bf16 features; one wave per node; 4 nodes/block.
__global__ __launch_bounds__(256) void gather1(const u32* __restrict__ h,       // [NNODES,64] bf16x2
                                               const int* __restrict__ row_ptr, const int* __restrict__ col_idx,
                                               const float* __restrict__ rin, const float* __restrict__ b1,
                                               u32* __restrict__ h1out, int nNodes) {
    int lane = threadIdx.x & 63;
    int node = blockIdx.x * 4 + (threadIdx.x >> 6);
    if (node >= nNodes) return;
    int beg = row_ptr[node], end = row_ptr[node + 1];
    float a0 = 0.f, a1 = 0.f;
    int e = beg;
    for (; e + 1 < end; e += 2) {
        int s0 = col_idx[e], s1 = col_idx[e + 1];
        u32 p0 = h[(size_t)s0 * 64 + lane];
        u32 p1 = h[(size_t)s1 * 64 + lane];
        a0 += bflo(p0) + bflo(p1);
        a1 += bfhi(p0) + bfhi(p1);
    }
    if (e < end) {
        u32 p = h[(size_t)col_idx[e] * 64 + lane];
        a0 += bflo(p);
        a1 += bfhi(p);
    }
    float r = rin[node];
    float v0 = fmaxf(a0 * r + b1[2 * lane + 0], 0.f);
    float v1 = fmaxf(a1 * r + b1[2 * lane + 1], 0.f);
    h1out[(size_t)node * 64 + lane] = ((u32)f2bf(v1) << 16) | f2bf(v0);
}

// ---- layer-2 gather + epilogue + final projection ----
// F=64 as 32 lanes x 2 bf16 features; half-wave per node; 8 nodes/block.
__global__ __launch_bounds__(256) void gather2(const u32* __restrict__ h2,      // [NNODES,32] bf16x2
                                               const int* __restrict__ row_ptr, const int* __restrict__ col_idx,
                                               const float* __restrict__ rin, const float* __restrict__ b2,
                                               const float* __restrict__ Wf, const float* __restrict__ bfv,
                                               float* __restrict__ logits, float* __restrict__ hidden, int nNodes) {
    int lane = threadIdx.x & 63;
    int l = lane & 31;
    int node = blockIdx.x * 8 + (threadIdx.x >> 5);
    if (node >= nNodes) return;
    int beg = row_ptr[node], end = row_ptr[node + 1];
    float a0 = 0.f, a1 = 0.f;
    int e = beg;
    for (; e + 1 < end; e += 2) {
        int s0 = col_idx[e], s1 = col_idx[e + 1];
        u32 p0 = h2[(size_t)s0 * 32 + l];
        u32 p1 = h2[(size_t)s1 * 32 + l];
        a0 += bflo(p0) + bflo(p1);
        a1 += bfhi(p0) + bfhi(p1);
    }
    if (e < end) {
        u32 p = h2[(size_t)col_idx[e] * 32 + l];
        a0 += bflo(p);
        a1 += bfhi(p);
    }
    float r = rin[node];
    float v0 = a0 * r + b2[2 * l + 0];
    float v1 = a1 * r + b2[2 * l + 1];
    hidden[(size_t)node * 64 + 2 * l + 0] = v0;
    hidden[(size_t)node * 64 + 2 * l + 1] = v1;
    float l0 = v0 * Wf[(2 * l) * 2 + 0] + v1 * Wf[(2 * l + 1) * 2 + 0];
    float l1 = v0 * Wf[(2 * l) * 2 + 1] + v1 * Wf[(2 * l + 1) * 2 + 1];
    #pragma unroll
    for (int off = 16; off > 0; off >>= 1) {
        l0 += __shfl_down(l0, off, 32);
        l1 += __shfl_down(l1, off, 32);
    }
    if (l == 0) {
        logits[(size_t)node * 2 + 0] = l0 + bfv[0];
        logits[(size_t)node * 2 + 1] = l1 + bfv[1];
    }
}

extern "C" void kernel_launch(void* const* d_in, const int* in_sizes, int n_in,
                              void* d_out, int out_size, void* d_ws, size_t ws_size,
                              hipStream_t stream) {
    const float* x   = (const float*)d_in[0];
    const float* W1  = (const float*)d_in[1];
    const float* b1  = (const float*)d_in[2];
    const float* W2  = (const float*)d_in[3];
    const float* b2  = (const float*)d_in[4];
    const float* Wf  = (const float*)d_in[5];
    const float* bfv = (const float*)d_in[6];
    const int* src = (const int*)d_in[7];
    const int* dst = (const int*)d_in[8];

    float* out_logits = (float*)d_out;
    float* out_hidden = (float*)d_out + 2 * NNODES;

    char* ws = (char*)d_ws;
    size_t off = 0;
    auto alloc = [&](size_t bytes) { void* p = ws + off; off += (bytes + 255) & ~(size_t)255; return p; };
    int*   cnt_out = (int*)alloc(NNODES * 4);
    int*   cnt_in  = (int*)alloc(NNODES * 4);
    float* rs_o    = (float*)alloc(NNODES * 4);
    float* rs_i    = (float*)alloc(NNODES * 4);
    int*   scanned = (int*)alloc(NNODES * 4);
    int*   partials= (int*)alloc(256 * 4);
    int*   offs    = (int*)alloc(256 * 4);
    int*   row_ptr = (int*)alloc((NNODES + 1) * 4);
    int*   rank    = (int*)alloc((size_t)NEDGES * 4);
    int*   col_idx = (int*)alloc((size_t)NEDGES * 4);
    u16*   h       = (u16*)alloc((size_t)NNODES * 128 * 2);   // layer1 transform, bf16 scaled
    u16*   h1      = (u16*)alloc((size_t)NNODES * 128 * 2);   // relu'd hidden, bf16
    u16*   h2      = (u16*)alloc((size_t)NNODES * 64 * 2);    // layer2 transform, bf16 scaled

    hipMemsetAsync(cnt_out, 0, NNODES * 4, stream);
    hipMemsetAsync(cnt_in,  0, NNODES * 4, stream);

    deg_rank_kernel<<<(NEDGES + 255) / 256, 256, 0, stream>>>(src, dst, cnt_out, cnt_in, rank, NEDGES);

    // CSR by dst (atomic-free placement via rank)
    scan_partial<<<NBLK, 256, 0, stream>>>(cnt_in, scanned, partials, NNODES);
    scan_offs<<<1, 256, 0, stream>>>(partials, offs, NBLK);
    scan_final_rs<<<NBLK, 256, 0, stream>>>(scanned, offs, cnt_in, cnt_out, row_ptr, rs_o, rs_i, NNODES);
    csr_place<<<(NEDGES + 255) / 256, 256, 0, stream>>>(src, dst, rank, row_ptr, col_idx, NEDGES);

    // layer 1
    gemm_scaled<256, 128, true><<<(NNODES + 63) / 64, 256, 0, stream>>>(x, W1, rs_o, h, NNODES);
    gather1<<<(NNODES + 3) / 4, 256, 0, stream>>>((const u32*)h, row_ptr, col_idx, rs_i, b1, (u32*)h1, NNODES);

    // layer 2
    gemm_scaled<128, 64, false><<<(NNODES + 63) / 64, 256, 0, stream>>>(h1, W2, rs_o, h2, NNODES);
    gather2<<<(NNODES + 7) / 8, 256, 0, stream>>>((const u32*)h2, row_ptr, col_idx, rs_i, b2, Wf, bfv,
                                                  out_logits, out_hidden, NNODES);
}

// Round 6
// 320.000 us; speedup vs baseline: 2.3825x; 1.0054x over previous
//
#include <hip/hip_runtime.h>
#include <hip/hip_bf16.h>
#include <cstdint>
#include <cstddef>

#define NNODES 50000
#define NEDGES 800000
#define NBLK   ((NNODES + 255) / 256)     // 196
// pass 1 (low byte, unstable OK): 256-thread blocks over 8192-element chunks
#define CHUNK1 8192
#define GA     98                          // ceil(NEDGES/CHUNK1)
#define GHHALF (256 * GA)                  // 25088
#define GHTOT  (2 * GHHALF)                // 50176 = 196*256
// pass 2 (high byte, STABLE): 1 wave per 2000-element chunk
#define SCB    400                         // chunks per dataset; 400*2000 = 800000 exact
#define C2     2000
#define GH2HALF (256 * SCB)                // 102400
#define GH2TOT  (2 * GH2HALF)              // 204800 = 800*256
#define NBE    ((NEDGES + 255) / 256)      // 3125

typedef unsigned short u16;
typedef unsigned int u32;
typedef short bfrag8 __attribute__((ext_vector_type(8)));
typedef float f32x4 __attribute__((ext_vector_type(4)));

__device__ __forceinline__ u16 f2bf(float f) {
    union { float f; uint32_t i; } v; v.f = f;
    uint32_t r = (v.i + 0x7FFFu + ((v.i >> 16) & 1u)) >> 16;
    return (u16)r;
}
__device__ __forceinline__ float bflo(u32 p) { union { uint32_t i; float f; } v; v.i = p << 16; return v.f; }
__device__ __forceinline__ float bfhi(u32 p) { union { uint32_t i; float f; } v; v.i = p & 0xFFFF0000u; return v.f; }

// ================= radix sort: pass 1 = low byte (unstable ok), pass 2 = high byte (STABLE) ====
// Joint layout for both passes: [A digits][B digits], digit-major then chunk ->
// exclusive scan gives A positions in [0,nE), B in [nE,2nE).
// A = edges keyed by dst (payload src, -> CSR); B = src keys alone (-> out-degree).

__global__ __launch_bounds__(256) void hist1(const int* __restrict__ dst, const int* __restrict__ src,
                                             u32* __restrict__ gh, int nE) {
    __shared__ u32 hist[256];
    hist[threadIdx.x] = 0;
    __syncthreads();
    int b = blockIdx.x;
    int dsB = (b >= GA);
    int bb = dsB ? b - GA : b;
    int beg = bb * CHUNK1, end = min(beg + CHUNK1, nE);
    for (int i = beg + threadIdx.x; i < end; i += 256) {
        u32 key = dsB ? (u32)src[i] : (u32)dst[i];
        atomicAdd(&hist[key & 255], 1);
    }
    __syncthreads();
    gh[dsB * GHHALF + threadIdx.x * GA + bb] = hist[threadIdx.x];
}

__global__ __launch_bounds__(256) void scatter1(const int* __restrict__ dst, const int* __restrict__ src,
                                                const u32* __restrict__ ex,
                                                uint2* __restrict__ pairA, u32* __restrict__ keyB, int nE) {
    __shared__ u32 base[256];
    __shared__ u32 lh[256];
    int b = blockIdx.x;
    int dsB = (b >= GA);
    int bb = dsB ? b - GA : b;
    base[threadIdx.x] = ex[dsB * GHHALF + threadIdx.x * GA + bb];
    lh[threadIdx.x] = 0;
    __syncthreads();
    int beg = bb * CHUNK1, end = min(beg + CHUNK1, nE);
    for (int i = beg + threadIdx.x; i < end; i += 256) {
        u32 key, pay = 0;
        if (dsB) key = (u32)src[i];
        else { key = (u32)dst[i]; pay = (u32)src[i]; }
        u32 d = key & 255;
        u32 r = atomicAdd(&lh[d], 1);
        u32 pos = base[d] + r;
        if (dsB) keyB[pos - nE] = key;
        else     pairA[pos] = make_uint2(key, pay);
    }
}

// pass-2 histogram: 4 waves/block, each wave owns one 2000-element chunk (wave-private LDS hist)
__global__ __launch_bounds__(256) void hist2(const uint2* __restrict__ pairA, const u32* __restrict__ keyB,
                                             u32* __restrict__ gh2, int nE) {
    __shared__ u32 hist[4][256];
    int wave = threadIdx.x >> 6, lane = threadIdx.x & 63;
    int cg = blockIdx.x * 4 + wave;           // 0 .. 2*SCB-1
    int dsB = (cg >= SCB);
    int cc = dsB ? cg - SCB : cg;
    for (int j = lane; j < 256; j += 64) hist[wave][j] = 0;
    __syncthreads();
    int beg = cc * C2, end = min(beg + C2, nE);
    for (int i = beg + lane; i < end; i += 64) {
        u32 key = dsB ? keyB[i] : pairA[i].x;
        atomicAdd(&hist[wave][(key >> 8) & 255], 1);
    }
    __syncthreads();
    for (int j = lane; j < 256; j += 64)
        gh2[dsB * GH2HALF + j * SCB + cc] = hist[wave][j];
}

// pass-2 STABLE scatter: wave-per-chunk; ballot-match groups, lane-order ranks,
// leader bumps per-wave LDS running counters (program order => cross-iteration stability).
__global__ __launch_bounds__(256) void scatter2_stable(const uint2* __restrict__ pairA, const u32* __restrict__ keyB,
                                                       const u32* __restrict__ ex,
                                                       u32* __restrict__ dstS, int* __restrict__ col_idx,
                                                       u32* __restrict__ srcS, int nE) {
    __shared__ u32 run[4][256];
    int wave = threadIdx.x >> 6, lane = threadIdx.x & 63;
    int cg = blockIdx.x * 4 + wave;
    int dsB = (cg >= SCB);
    int cc = dsB ? cg - SCB : cg;
    for (int j = lane; j < 256; j += 64) run[wave][j] = ex[dsB * GH2HALF + j * SCB + cc];
    __syncthreads();
    int beg = cc * C2, end = min(beg + C2, nE);
    for (int i0 = beg; i0 < end; i0 += 64) {
        int i = i0 + lane;
        int active = (i < end);
        u32 key = 0, pay = 0;
        if (active) {
            if (dsB) key = keyB[i];
            else { uint2 p = pairA[i]; key = p.x; pay = p.y; }
        }
        u32 d = (key >> 8) & 255;
        unsigned long long m = __ballot(active);
        #pragma unroll
        for (int b = 0; b < 8; b++) {
            unsigned long long bb_ = __ballot(active && ((d >> b) & 1));
            m &= ((d >> b) & 1) ? bb_ : ~bb_;
        }
        if (active) {
            int lanerank = __popcll(m & ((1ull << lane) - 1ull));
            int leader = __ffsll((long long)m) - 1;
            u32 base = 0;
            if (lane == leader) base = atomicAdd(&run[wave][d], (u32)__popcll(m));
            base = (u32)__shfl((int)base, leader, 64);
            u32 pos = base + (u32)lanerank;
            if (dsB) srcS[pos - nE] = key;
            else { dstS[pos] = key; col_idx[pos] = (int)pay; }
        }
    }
}

// ---- scan step 1: per-block inclusive scan + block totals ----
__global__ __launch_bounds__(256) void scan_partial(const int* __restrict__ cnt, int* __restrict__ scanned,
                                                    int* __restrict__ partials, int n) {
    __shared__ int sd[256];
    int t = threadIdx.x;
    int i = blockIdx.x * 256 + t;
    int v = (i < n) ? cnt[i] : 0;
    sd[t] = v;
    __syncthreads();
    #pragma unroll
    for (int o = 1; o < 256; o <<= 1) {
        int add = (t >= o) ? sd[t - o] : 0;
        __syncthreads();
        sd[t] += add;
        __syncthreads();
    }
    if (i < n) scanned[i] = sd[t];
    if (t == 255) partials[blockIdx.x] = sd[255];
}

// ---- scan step 2: exclusive scan of block totals, nb <= 1024 (single block, 4 per thread) ----
__global__ __launch_bounds__(256) void scan_offs(const int* __restrict__ partials, int* __restrict__ offs, int nb) {
    __shared__ int sd[256];
    int t = threadIdx.x;
    int v[4]; int s = 0;
    #pragma unroll
    for (int j = 0; j < 4; j++) { int idx = t * 4 + j; v[j] = (idx < nb) ? partials[idx] : 0; s += v[j]; }
    sd[t] = s;
    __syncthreads();
    #pragma unroll
    for (int o = 1; o < 256; o <<= 1) {
        int add = (t >= o) ? sd[t - o] : 0;
        __syncthreads();
        sd[t] += add;
        __syncthreads();
    }
    int base = sd[t] - s;   // exclusive base for this thread's 4 entries
    #pragma unroll
    for (int j = 0; j < 4; j++) { int idx = t * 4 + j; if (idx < nb) offs[idx] = base; base += v[j]; }
}

// ---- scan step 3: write exclusive scan in-place over gh ----
__global__ __launch_bounds__(256) void scan_final_ex(const int* __restrict__ scanned, const int* __restrict__ offs,
                                                     u32* __restrict__ gh, int n) {
    int i = blockIdx.x * 256 + threadIdx.x;
    if (i < n) {
        int incl = scanned[i] + offs[blockIdx.x];
        gh[i] = (u32)(incl - (int)gh[i]);
    }
}

// ---- boundary detection on sorted keys -> row pointer arrays ----
__global__ __launch_bounds__(256) void bounds_kernel(const u32* __restrict__ dstS, const u32* __restrict__ srcS,
                                                     int* __restrict__ rp, int* __restrict__ rps, int nE) {
    int dsB = (blockIdx.x >= NBE);
    int e = (blockIdx.x - (dsB ? NBE : 0)) * 256 + threadIdx.x;
    if (e >= nE) return;
    const u32* ks = dsB ? srcS : dstS;
    int* out = dsB ? rps : rp;
    int k = (int)ks[e];
    int kp = e ? (int)ks[e - 1] : -1;
    if (k != kp)
        for (int n = kp + 1; n <= k; n++) out[n] = e;
    if (e == nE - 1)
        for (int n = k + 1; n <= NNODES; n++) out[n] = nE;
}

// ---- norms from row-pointer diffs ----
__global__ __launch_bounds__(256) void rs_kernel(const int* __restrict__ rp, const int* __restrict__ rps,
                                                 float* __restrict__ rs_i, float* __restrict__ rs_o, int n) {
    int i = blockIdx.x * 256 + threadIdx.x;
    if (i < n) {
        int dI = rp[i + 1] - rp[i];   if (dI < 1) dI = 1;
        int dO = rps[i + 1] - rps[i]; if (dO < 1) dO = 1;
        rs_i[i] = rsqrtf((float)dI);
        rs_o[i] = rsqrtf((float)dO);
    }
}

// ================= dense compute (unchanged, verified rounds 2-4) ==========

template <int K, int N, bool AF32>
__global__ __launch_bounds__(256) void gemm_scaled(const void* __restrict__ A_, const float* __restrict__ W,
                                                   const float* __restrict__ rs, u16* __restrict__ out, int M) {
    __shared__ __align__(16) u16 Wl[K * N];
    constexpr int NO4 = N / 4;
    for (int idx = threadIdx.x; idx < K * NO4; idx += 256) {
        int k = idx / NO4;
        int n0 = (idx - k * NO4) * 4;
        const float4 w = *(const float4*)(W + k * N + n0);
        int base = (k >> 3) * (N * 8) + (k & 7);
        Wl[base + (n0 + 0) * 8] = f2bf(w.x);
        Wl[base + (n0 + 1) * 8] = f2bf(w.y);
        Wl[base + (n0 + 2) * 8] = f2bf(w.z);
        Wl[base + (n0 + 3) * 8] = f2bf(w.w);
    }
    __syncthreads();

    const int lane = threadIdx.x & 63;
    const int wave = threadIdx.x >> 6;
    const int m = lane & 15;
    const int q = lane >> 4;
    const int row0 = blockIdx.x * 64 + wave * 16;

    int rowa = row0 + m; if (rowa > M - 1) rowa = M - 1;

    constexpr int NT = N / 16;
    f32x4 acc[NT];
    #pragma unroll
    for (int t = 0; t < NT; t++) acc[t] = (f32x4){0.f, 0.f, 0.f, 0.f};

    for (int kc = 0; kc < K; kc += 32) {
        bfrag8 af;
        if constexpr (AF32) {
            const float* ap = (const float*)A_ + (size_t)rowa * K + q * 8 + kc;
            const float4 x0 = *(const float4*)(ap);
            const float4 x1 = *(const float4*)(ap + 4);
            af[0] = (short)f2bf(x0.x); af[1] = (short)f2bf(x0.y);
            af[2] = (short)f2bf(x0.z); af[3] = (short)f2bf(x0.w);
            af[4] = (short)f2bf(x1.x); af[5] = (short)f2bf(x1.y);
            af[6] = (short)f2bf(x1.z); af[7] = (short)f2bf(x1.w);
        } else {
            const u16* ap = (const u16*)A_ + (size_t)rowa * K + q * 8 + kc;
            af = *(const bfrag8*)ap;
        }
        const u16* bbase = &Wl[((kc >> 3) + q) * (N * 8) + m * 8];
        #pragma unroll
        for (int t = 0; t < NT; t++) {
            bfrag8 bf_ = *(const bfrag8*)(bbase + t * 128);
            acc[t] = __builtin_amdgcn_mfma_f32_16x16x32_bf16(af, bf_, acc[t], 0, 0, 0);
        }
    }
    #pragma unroll
    for (int r = 0; r < 4; r++) {
        int gr = row0 + q * 4 + r;
        if (gr < M) {
            float s = rs[gr];
            #pragma unroll
            for (int t = 0; t < NT; t++)
                out[(size_t)gr * N + t * 16 + m] = f2bf(acc[t][r] * s);
        }
    }
}

__global__ __launch_bounds__(256) void gather1(const u32* __restrict__ h,
                                               const int* __restrict__ row_ptr, const int* __restrict__ col_idx,
                                               const float* __restrict__ rin, const float* __restrict__ b1,
                                               u32* __restrict__ h1out, int nNodes) {
    int lane = threadIdx.x & 63;
    int node = blockIdx.x * 4 + (threadIdx.x >> 6);
    if (node >= nNodes) return;
    int beg = row_ptr[node], end = row_ptr[node + 1];
    float a0 = 0.f, a1 = 0.f;
    int e = beg;
    for (; e + 1 < end; e += 2) {
        int s0 = col_idx[e], s1 = col_idx[e + 1];
        u32 p0 = h[(size_t)s0 * 64 + lane];
        u32 p1 = h[(size_t)s1 * 64 + lane];
        a0 += bflo(p0) + bflo(p1);
        a1 += bfhi(p0) + bfhi(p1);
    }
    if (e < end) {
        u32 p = h[(size_t)col_idx[e] * 64 + lane];
        a0 += bflo(p);
        a1 += bfhi(p);
    }
    float r = rin[node];
    float v0 = fmaxf(a0 * r + b1[2 * lane + 0], 0.f);
    float v1 = fmaxf(a1 * r + b1[2 * lane + 1], 0.f);
    h1out[(size_t)node * 64 + lane] = ((u32)f2bf(v1) << 16) | f2bf(v0);
}

__global__ __launch_bounds__(256) void gather2(const u32* __restrict__ h2,
                                               const int* __restrict__ row_ptr, const int* __restrict__ col_idx,
                                               const float* __restrict__ rin, const float* __restrict__ b2,
                                               const float* __restrict__ Wf, const float* __restrict__ bfv,
                                               float* __restrict__ logits, float* __restrict__ hidden, int nNodes) {
    int lane = threadIdx.x & 63;
    int l = lane & 31;
    int node = blockIdx.x * 8 + (threadIdx.x >> 5);
    if (node >= nNodes) return;
    int beg = row_ptr[node], end = row_ptr[node + 1];
    float a0 = 0.f, a1 = 0.f;
    int e = beg;
    for (; e + 1 < end; e += 2) {
        int s0 = col_idx[e], s1 = col_idx[e + 1];
        u32 p0 = h2[(size_t)s0 * 32 + l];
        u32 p1 = h2[(size_t)s1 * 32 + l];
        a0 += bflo(p0) + bflo(p1);
        a1 += bfhi(p0) + bfhi(p1);
    }
    if (e < end) {
        u32 p = h2[(size_t)col_idx[e] * 32 + l];
        a0 += bflo(p);
        a1 += bfhi(p);
    }
    float r = rin[node];
    float v0 = a0 * r + b2[2 * l + 0];
    float v1 = a1 * r + b2[2 * l + 1];
    hidden[(size_t)node * 64 + 2 * l + 0] = v0;
    hidden[(size_t)node * 64 + 2 * l + 1] = v1;
    float l0 = v0 * Wf[(2 * l) * 2 + 0] + v1 * Wf[(2 * l + 1) * 2 + 0];
    float l1 = v0 * Wf[(2 * l) * 2 + 1] + v1 * Wf[(2 * l + 1) * 2 + 1];
    #pragma unroll
    for (int off = 16; off > 0; off >>= 1) {
        l0 += __shfl_down(l0, off, 32);
        l1 += __shfl_down(l1, off, 32);
    }
    if (l == 0) {
        logits[(size_t)node * 2 + 0] = l0 + bfv[0];
        logits[(size_t)node * 2 + 1] = l1 + bfv[1];
    }
}

extern "C" void kernel_launch(void* const* d_in, const int* in_sizes, int n_in,
                              void* d_out, int out_size, void* d_ws, size_t ws_size,
                              hipStream_t stream) {
    const float* x   = (const float*)d_in[0];
    const float* W1  = (const float*)d_in[1];
    const float* b1  = (const float*)d_in[2];
    const float* W2  = (const float*)d_in[3];
    const float* b2  = (const float*)d_in[4];
    const float* Wf  = (const float*)d_in[5];
    const float* bfv = (const float*)d_in[6];
    const int* src = (const int*)d_in[7];
    const int* dst = (const int*)d_in[8];

    float* out_logits = (float*)d_out;
    float* out_hidden = (float*)d_out + 2 * NNODES;

    char* ws = (char*)d_ws;
    size_t off = 0;
    auto alloc = [&](size_t bytes) { void* p = ws + off; off += (bytes + 255) & ~(size_t)255; return p; };
    u32*   gh1     = (u32*)alloc(GHTOT * 4);
    u32*   gh2     = (u32*)alloc(GH2TOT * 4);
    int*   scanned = (int*)alloc(GH2TOT * 4);      // reused for both scans (GH2TOT >= GHTOT)
    int*   partials= (int*)alloc(1024 * 4);
    int*   offs    = (int*)alloc(1024 * 4);
    uint2* pairA   = (uint2*)alloc((size_t)NEDGES * 8);
    u32*   keyB    = (u32*)alloc((size_t)NEDGES * 4);
    u32*   dstS    = (u32*)alloc((size_t)NEDGES * 4);
    int*   col_idx = (int*)alloc((size_t)NEDGES * 4);
    u32*   srcS    = (u32*)alloc((size_t)NEDGES * 4);
    int*   row_ptr = (int*)alloc((NNODES + 1) * 4);
    int*   rp_src  = (int*)alloc((NNODES + 1) * 4);
    float* rs_o    = (float*)alloc(NNODES * 4);
    float* rs_i    = (float*)alloc(NNODES * 4);
    u16*   h       = (u16*)alloc((size_t)NNODES * 128 * 2);
    u16*   h1      = (u16*)alloc((size_t)NNODES * 128 * 2);
    u16*   h2      = (u16*)alloc((size_t)NNODES * 64 * 2);

    // ---- pass 1 (low byte, unstable) ----
    hist1<<<2 * GA, 256, 0, stream>>>(dst, src, gh1, NEDGES);
    scan_partial<<<GHTOT / 256, 256, 0, stream>>>((const int*)gh1, scanned, partials, GHTOT);
    scan_offs<<<1, 256, 0, stream>>>(partials, offs, GHTOT / 256);
    scan_final_ex<<<GHTOT / 256, 256, 0, stream>>>(scanned, offs, gh1, GHTOT);
    scatter1<<<2 * GA, 256, 0, stream>>>(dst, src, gh1, pairA, keyB, NEDGES);

    // ---- pass 2 (high byte, stable) ----
    hist2<<<2 * SCB / 4, 256, 0, stream>>>(pairA, keyB, gh2, NEDGES);
    scan_partial<<<GH2TOT / 256, 256, 0, stream>>>((const int*)gh2, scanned, partials, GH2TOT);
    scan_offs<<<1, 256, 0, stream>>>(partials, offs, GH2TOT / 256);
    scan_final_ex<<<GH2TOT / 256, 256, 0, stream>>>(scanned, offs, gh2, GH2TOT);
    scatter2_stable<<<2 * SCB / 4, 256, 0, stream>>>(pairA, keyB, gh2, dstS, col_idx, srcS, NEDGES);

    // ---- row pointers + norms ----
    bounds_kernel<<<2 * NBE, 256, 0, stream>>>(dstS, srcS, row_ptr, rp_src, NEDGES);
    rs_kernel<<<NBLK, 256, 0, stream>>>(row_ptr, rp_src, rs_i, rs_o, NNODES);

    // ---- layer 1 ----
    gemm_scaled<256, 128, true><<<(NNODES + 63) / 64, 256, 0, stream>>>(x, W1, rs_o, h, NNODES);
    gather1<<<(NNODES + 3) / 4, 256, 0, stream>>>((const u32*)h, row_ptr, col_idx, rs_i, b1, (u32*)h1, NNODES);

    // ---- layer 2 ----
    gemm_scaled<128, 64, false><<<(NNODES + 63) / 64, 256, 0, stream>>>(h1, W2, rs_o, h2, NNODES);
    gather2<<<(NNODES + 7) / 8, 256, 0, stream>>>((const u32*)h2, row_ptr, col_idx, rs_i, b2, Wf, bfv,
                                                  out_logits, out_hidden, NNODES);
}

// Round 7
// 288.168 us; speedup vs baseline: 2.6457x; 1.1105x over previous
//
#include <hip/hip_runtime.h>
#include <hip/hip_bf16.h>
#include <cstdint>
#include <cstddef>

#define NNODES 50000
#define NEDGES 800000
#define NBLK   ((NNODES + 255) / 256)     // 196
// pass 1 (low byte of key, unstable OK): 256-thread blocks over 8192-element chunks
#define CHUNK1 8192
#define GA     98                          // ceil(NEDGES/CHUNK1)
#define GHHALF (256 * GA)                  // 25088
#define GHTOT  (2 * GHHALF)                // 50176 = 196*256
// pass 2 (high byte, STABLE): 1 wave per 2000-element chunk
#define SCB    400                         // chunks per dataset; 400*2000 = 800000 exact
#define C2     2000
#define GH2HALF (256 * SCB)                // 102400
#define GH2TOT  (2 * GH2HALF)              // 204800 = 800*256
#define NBE    ((NEDGES + 255) / 256)      // 3125

typedef unsigned short u16;
typedef unsigned int u32;
typedef short bfrag8 __attribute__((ext_vector_type(8)));
typedef float f32x4 __attribute__((ext_vector_type(4)));

__device__ __forceinline__ u16 f2bf(float f) {
    union { float f; uint32_t i; } v; v.f = f;
    uint32_t r = (v.i + 0x7FFFu + ((v.i >> 16) & 1u)) >> 16;
    return (u16)r;
}
__device__ __forceinline__ float bflo(u32 p) { union { uint32_t i; float f; } v; v.i = p << 16; return v.f; }
__device__ __forceinline__ float bfhi(u32 p) { union { uint32_t i; float f; } v; v.i = p & 0xFFFF0000u; return v.f; }

// ============ radix sort of packed u32 elements ============
// element: dataset A (CSR) = (dst<<16)|src ; dataset B (out-degree) = src<<16.
// Sort key = element>>16 (the node id). pass-1 digit = (el>>16)&255, pass-2 digit = el>>24.
// Joint layout [A | B]: exclusive scan gives A positions in [0,nE), B in [nE,2nE).
// The final sorted array IS the CSR: col = el&0xFFFF, boundary key = el>>16.

__global__ __launch_bounds__(256) void hist1(const int* __restrict__ dst, const int* __restrict__ src,
                                             u32* __restrict__ gh, int nE) {
    __shared__ u32 hist[256];
    hist[threadIdx.x] = 0;
    __syncthreads();
    int b = blockIdx.x;
    int dsB = (b >= GA);
    int bb = dsB ? b - GA : b;
    int beg = bb * CHUNK1, end = min(beg + CHUNK1, nE);
    for (int i = beg + threadIdx.x; i < end; i += 256) {
        u32 d = dsB ? ((u32)src[i] & 255u) : ((u32)dst[i] & 255u);
        atomicAdd(&hist[d], 1);
    }
    __syncthreads();
    gh[dsB * GHHALF + threadIdx.x * GA + bb] = hist[threadIdx.x];
}

__global__ __launch_bounds__(256) void scatter1(const int* __restrict__ dst, const int* __restrict__ src,
                                                const u32* __restrict__ ex, u32* __restrict__ sbuf, int nE) {
    __shared__ u32 base[256];
    __shared__ u32 lh[256];
    int b = blockIdx.x;
    int dsB = (b >= GA);
    int bb = dsB ? b - GA : b;
    base[threadIdx.x] = ex[dsB * GHHALF + threadIdx.x * GA + bb];
    lh[threadIdx.x] = 0;
    __syncthreads();
    int beg = bb * CHUNK1, end = min(beg + CHUNK1, nE);
    for (int i = beg + threadIdx.x; i < end; i += 256) {
        u32 el = dsB ? ((u32)src[i] << 16) : (((u32)dst[i] << 16) | (u32)src[i]);
        u32 d = (el >> 16) & 255u;
        u32 r = atomicAdd(&lh[d], 1);
        sbuf[base[d] + r] = el;    // A lands in [0,nE), B in [nE,2nE)
    }
}

// pass-2 histogram: 4 waves/block, each wave owns one 2000-element chunk of pass-1 output
__global__ __launch_bounds__(256) void hist2(const u32* __restrict__ sbuf, u32* __restrict__ gh2, int nE) {
    __shared__ u32 hist[4][256];
    int wave = threadIdx.x >> 6, lane = threadIdx.x & 63;
    int cg = blockIdx.x * 4 + wave;           // 0 .. 2*SCB-1
    int dsB = (cg >= SCB);
    int cc = dsB ? cg - SCB : cg;
    for (int j = lane; j < 256; j += 64) hist[wave][j] = 0;
    __syncthreads();
    const u32* in = sbuf + (size_t)dsB * nE;
    int beg = cc * C2, end = min(beg + C2, nE);
    for (int i = beg + lane; i < end; i += 64)
        atomicAdd(&hist[wave][in[i] >> 24], 1);
    __syncthreads();
    for (int j = lane; j < 256; j += 64)
        gh2[dsB * GH2HALF + j * SCB + cc] = hist[wave][j];
}

// pass-2 STABLE scatter: wave-per-chunk; ballot-match groups, lane-order ranks,
// leader bumps per-wave LDS running counters (program order => cross-iteration stability).
__global__ __launch_bounds__(256) void scatter2_stable(const u32* __restrict__ sbuf, const u32* __restrict__ ex,
                                                       u32* __restrict__ sorted, int nE) {
    __shared__ u32 run[4][256];
    int wave = threadIdx.x >> 6, lane = threadIdx.x & 63;
    int cg = blockIdx.x * 4 + wave;
    int dsB = (cg >= SCB);
    int cc = dsB ? cg - SCB : cg;
    for (int j = lane; j < 256; j += 64) run[wave][j] = ex[dsB * GH2HALF + j * SCB + cc];
    __syncthreads();
    const u32* in = sbuf + (size_t)dsB * nE;
    int beg = cc * C2, end = min(beg + C2, nE);
    for (int i0 = beg; i0 < end; i0 += 64) {
        int i = i0 + lane;
        int active = (i < end);
        u32 el = active ? in[i] : 0;
        u32 d = el >> 24;
        unsigned long long m = __ballot(active);
        #pragma unroll
        for (int b = 0; b < 8; b++) {
            unsigned long long bb_ = __ballot(active && ((d >> b) & 1));
            m &= ((d >> b) & 1) ? bb_ : ~bb_;
        }
        if (active) {
            int lanerank = __popcll(m & ((1ull << lane) - 1ull));
            int leader = __ffsll((long long)m) - 1;
            u32 base = 0;
            if (lane == leader) base = atomicAdd(&run[wave][d], (u32)__popcll(m));
            base = (u32)__shfl((int)base, leader, 64);
            sorted[base + (u32)lanerank] = el;   // A in [0,nE), B in [nE,2nE)
        }
    }
}

// ---- scan step 1: per-block inclusive scan + block totals ----
__global__ __launch_bounds__(256) void scan_partial(const int* __restrict__ cnt, int* __restrict__ scanned,
                                                    int* __restrict__ partials, int n) {
    __shared__ int sd[256];
    int t = threadIdx.x;
    int i = blockIdx.x * 256 + t;
    int v = (i < n) ? cnt[i] : 0;
    sd[t] = v;
    __syncthreads();
    #pragma unroll
    for (int o = 1; o < 256; o <<= 1) {
        int add = (t >= o) ? sd[t - o] : 0;
        __syncthreads();
        sd[t] += add;
        __syncthreads();
    }
    if (i < n) scanned[i] = sd[t];
    if (t == 255) partials[blockIdx.x] = sd[255];
}

// ---- scan step 2: exclusive scan of block totals, nb <= 1024 ----
__global__ __launch_bounds__(256) void scan_offs(const int* __restrict__ partials, int* __restrict__ offs, int nb) {
    __shared__ int sd[256];
    int t = threadIdx.x;
    int v[4]; int s = 0;
    #pragma unroll
    for (int j = 0; j < 4; j++) { int idx = t * 4 + j; v[j] = (idx < nb) ? partials[idx] : 0; s += v[j]; }
    sd[t] = s;
    __syncthreads();
    #pragma unroll
    for (int o = 1; o < 256; o <<= 1) {
        int add = (t >= o) ? sd[t - o] : 0;
        __syncthreads();
        sd[t] += add;
        __syncthreads();
    }
    int base = sd[t] - s;
    #pragma unroll
    for (int j = 0; j < 4; j++) { int idx = t * 4 + j; if (idx < nb) offs[idx] = base; base += v[j]; }
}

// ---- scan step 3: write exclusive scan in-place over gh ----
__global__ __launch_bounds__(256) void scan_final_ex(const int* __restrict__ scanned, const int* __restrict__ offs,
                                                     u32* __restrict__ gh, int n) {
    int i = blockIdx.x * 256 + threadIdx.x;
    if (i < n) {
        int incl = scanned[i] + offs[blockIdx.x];
        gh[i] = (u32)(incl - (int)gh[i]);
    }
}

// ---- boundary detection on sorted keys -> row pointer arrays (A: rp by dst, B: rps by src) ----
__global__ __launch_bounds__(256) void bounds_kernel(const u32* __restrict__ sorted,
                                                     int* __restrict__ rp, int* __restrict__ rps, int nE) {
    int dsB = (blockIdx.x >= NBE);
    int e = (blockIdx.x - (dsB ? NBE : 0)) * 256 + threadIdx.x;
    if (e >= nE) return;
    const u32* ks = sorted + (size_t)dsB * nE;
    int* out = dsB ? rps : rp;
    int k = (int)(ks[e] >> 16);
    int kp = e ? (int)(ks[e - 1] >> 16) : -1;
    if (k != kp)
        for (int n = kp + 1; n <= k; n++) out[n] = e;
    if (e == nE - 1)
        for (int n = k + 1; n <= NNODES; n++) out[n] = nE;
}

// ============ dense compute ============

// out_bf16[M,N] = bf16round((A[M,K] @ W[K,N]) * rsqrt(max(deg_out,1)))  — deg from rp_src diffs
template <int K, int N, bool AF32>
__global__ __launch_bounds__(256) void gemm_scaled(const void* __restrict__ A_, const float* __restrict__ W,
                                                   const int* __restrict__ rp_src, u16* __restrict__ out, int M) {
    __shared__ __align__(16) u16 Wl[K * N];
    constexpr int NO4 = N / 4;
    for (int idx = threadIdx.x; idx < K * NO4; idx += 256) {
        int k = idx / NO4;
        int n0 = (idx - k * NO4) * 4;
        const float4 w = *(const float4*)(W + k * N + n0);
        int base = (k >> 3) * (N * 8) + (k & 7);
        Wl[base + (n0 + 0) * 8] = f2bf(w.x);
        Wl[base + (n0 + 1) * 8] = f2bf(w.y);
        Wl[base + (n0 + 2) * 8] = f2bf(w.z);
        Wl[base + (n0 + 3) * 8] = f2bf(w.w);
    }
    __syncthreads();

    const int lane = threadIdx.x & 63;
    const int wave = threadIdx.x >> 6;
    const int m = lane & 15;
    const int q = lane >> 4;
    const int row0 = blockIdx.x * 64 + wave * 16;

    int rowa = row0 + m; if (rowa > M - 1) rowa = M - 1;

    constexpr int NT = N / 16;
    f32x4 acc[NT];
    #pragma unroll
    for (int t = 0; t < NT; t++) acc[t] = (f32x4){0.f, 0.f, 0.f, 0.f};

    for (int kc = 0; kc < K; kc += 32) {
        bfrag8 af;
        if constexpr (AF32) {
            const float* ap = (const float*)A_ + (size_t)rowa * K + q * 8 + kc;
            const float4 x0 = *(const float4*)(ap);
            const float4 x1 = *(const float4*)(ap + 4);
            af[0] = (short)f2bf(x0.x); af[1] = (short)f2bf(x0.y);
            af[2] = (short)f2bf(x0.z); af[3] = (short)f2bf(x0.w);
            af[4] = (short)f2bf(x1.x); af[5] = (short)f2bf(x1.y);
            af[6] = (short)f2bf(x1.z); af[7] = (short)f2bf(x1.w);
        } else {
            const u16* ap = (const u16*)A_ + (size_t)rowa * K + q * 8 + kc;
            af = *(const bfrag8*)ap;
        }
        const u16* bbase = &Wl[((kc >> 3) + q) * (N * 8) + m * 8];
        #pragma unroll
        for (int t = 0; t < NT; t++) {
            bfrag8 bf_ = *(const bfrag8*)(bbase + t * 128);
            acc[t] = __builtin_amdgcn_mfma_f32_16x16x32_bf16(af, bf_, acc[t], 0, 0, 0);
        }
    }
    #pragma unroll
    for (int r = 0; r < 4; r++) {
        int gr = row0 + q * 4 + r;
        if (gr < M) {
            int dO = rp_src[gr + 1] - rp_src[gr]; if (dO < 1) dO = 1;
            float s = rsqrtf((float)dO);
            #pragma unroll
            for (int t = 0; t < NT; t++)
                out[(size_t)gr * N + t * 16 + m] = f2bf(acc[t][r] * s);
        }
    }
}

// ---- layer-1 gather + epilogue: unroll-4 for MLP; col = sorted[e]&0xFFFF ----
__global__ __launch_bounds__(256) void gather1(const u32* __restrict__ h, const int* __restrict__ row_ptr,
                                               const u32* __restrict__ sorted, const float* __restrict__ b1,
                                               u32* __restrict__ h1out, int nNodes) {
    int lane = threadIdx.x & 63;
    int node = blockIdx.x * 4 + (threadIdx.x >> 6);
    if (node >= nNodes) return;
    int beg = row_ptr[node], end = row_ptr[node + 1];
    float a0 = 0.f, a1 = 0.f;
    int e = beg;
    for (; e + 3 < end; e += 4) {
        int s0 = (int)(sorted[e + 0] & 0xFFFFu);
        int s1 = (int)(sorted[e + 1] & 0xFFFFu);
        int s2 = (int)(sorted[e + 2] & 0xFFFFu);
        int s3 = (int)(sorted[e + 3] & 0xFFFFu);
        u32 p0 = h[(size_t)s0 * 64 + lane];
        u32 p1 = h[(size_t)s1 * 64 + lane];
        u32 p2 = h[(size_t)s2 * 64 + lane];
        u32 p3 = h[(size_t)s3 * 64 + lane];
        a0 += (bflo(p0) + bflo(p1)) + (bflo(p2) + bflo(p3));
        a1 += (bfhi(p0) + bfhi(p1)) + (bfhi(p2) + bfhi(p3));
    }
    for (; e < end; e++) {
        u32 p = h[(size_t)(sorted[e] & 0xFFFFu) * 64 + lane];
        a0 += bflo(p);
        a1 += bfhi(p);
    }
    int dI = end - beg; if (dI < 1) dI = 1;
    float r = rsqrtf((float)dI);
    float v0 = fmaxf(a0 * r + b1[2 * lane + 0], 0.f);
    float v1 = fmaxf(a1 * r + b1[2 * lane + 1], 0.f);
    h1out[(size_t)node * 64 + lane] = ((u32)f2bf(v1) << 16) | f2bf(v0);
}

// ---- layer-2 gather + epilogue + final projection: half-wave per node, unroll-4 ----
__global__ __launch_bounds__(256) void gather2(const u32* __restrict__ h2, const int* __restrict__ row_ptr,
                                               const u32* __restrict__ sorted, const float* __restrict__ b2,
                                               const float* __restrict__ Wf, const float* __restrict__ bfv,
                                               float* __restrict__ logits, float* __restrict__ hidden, int nNodes) {
    int lane = threadIdx.x & 63;
    int l = lane & 31;
    int node = blockIdx.x * 8 + (threadIdx.x >> 5);
    if (node >= nNodes) return;
    int beg = row_ptr[node], end = row_ptr[node + 1];
    float a0 = 0.f, a1 = 0.f;
    int e = beg;
    for (; e + 3 < end; e += 4) {
        int s0 = (int)(sorted[e + 0] & 0xFFFFu);
        int s1 = (int)(sorted[e + 1] & 0xFFFFu);
        int s2 = (int)(sorted[e + 2] & 0xFFFFu);
        int s3 = (int)(sorted[e + 3] & 0xFFFFu);
        u32 p0 = h2[(size_t)s0 * 32 + l];
        u32 p1 = h2[(size_t)s1 * 32 + l];
        u32 p2 = h2[(size_t)s2 * 32 + l];
        u32 p3 = h2[(size_t)s3 * 32 + l];
        a0 += (bflo(p0) + bflo(p1)) + (bflo(p2) + bflo(p3));
        a1 += (bfhi(p0) + bfhi(p1)) + (bfhi(p2) + bfhi(p3));
    }
    for (; e < end; e++) {
        u32 p = h2[(size_t)(sorted[e] & 0xFFFFu) * 32 + l];
        a0 += bflo(p);
        a1 += bfhi(p);
    }
    int dI = end - beg; if (dI < 1) dI = 1;
    float r = rsqrtf((float)dI);
    float v0 = a0 * r + b2[2 * l + 0];
    float v1 = a1 * r + b2[2 * l + 1];
    hidden[(size_t)node * 64 + 2 * l + 0] = v0;
    hidden[(size_t)node * 64 + 2 * l + 1] = v1;
    float l0 = v0 * Wf[(2 * l) * 2 + 0] + v1 * Wf[(2 * l + 1) * 2 + 0];
    float l1 = v0 * Wf[(2 * l) * 2 + 1] + v1 * Wf[(2 * l + 1) * 2 + 1];
    #pragma unroll
    for (int off = 16; off > 0; off >>= 1) {
        l0 += __shfl_down(l0, off, 32);
        l1 += __shfl_down(l1, off, 32);
    }
    if (l == 0) {
        logits[(size_t)node * 2 + 0] = l0 + bfv[0];
        logits[(size_t)node * 2 + 1] = l1 + bfv[1];
    }
}

extern "C" void kernel_launch(void* const* d_in, const int* in_sizes, int n_in,
                              void* d_out, int out_size, void* d_ws, size_t ws_size,
                              hipStream_t stream) {
    const float* x   = (const float*)d_in[0];
    const float* W1  = (const float*)d_in[1];
    const float* b1  = (const float*)d_in[2];
    const float* W2  = (const float*)d_in[3];
    const float* b2  = (const float*)d_in[4];
    const float* Wf  = (const float*)d_in[5];
    const float* bfv = (const float*)d_in[6];
    const int* src = (const int*)d_in[7];
    const int* dst = (const int*)d_in[8];

    float* out_logits = (float*)d_out;
    float* out_hidden = (float*)d_out + 2 * NNODES;

    char* ws = (char*)d_ws;
    size_t off = 0;
    auto alloc = [&](size_t bytes) { void* p = ws + off; off += (bytes + 255) & ~(size_t)255; return p; };
    u32*   gh1     = (u32*)alloc(GHTOT * 4);
    u32*   gh2     = (u32*)alloc(GH2TOT * 4);
    int*   scanned = (int*)alloc(GH2TOT * 4);      // reused by both scans
    int*   partials= (int*)alloc(1024 * 4);
    int*   offs    = (int*)alloc(1024 * 4);
    u32*   sbuf    = (u32*)alloc((size_t)2 * NEDGES * 4);  // pass-1 output, packed
    u32*   sorted  = (u32*)alloc((size_t)2 * NEDGES * 4);  // pass-2 output = CSR + degree keys
    int*   row_ptr = (int*)alloc((NNODES + 1) * 4);
    int*   rp_src  = (int*)alloc((NNODES + 1) * 4);
    u16*   h       = (u16*)alloc((size_t)NNODES * 128 * 2);
    u16*   h1      = (u16*)alloc((size_t)NNODES * 128 * 2);
    u16*   h2      = (u16*)alloc((size_t)NNODES * 64 * 2);

    // ---- pass 1 (low byte of node id, unstable) ----
    hist1<<<2 * GA, 256, 0, stream>>>(dst, src, gh1, NEDGES);
    scan_partial<<<GHTOT / 256, 256, 0, stream>>>((const int*)gh1, scanned, partials, GHTOT);
    scan_offs<<<1, 256, 0, stream>>>(partials, offs, GHTOT / 256);
    scan_final_ex<<<GHTOT / 256, 256, 0, stream>>>(scanned, offs, gh1, GHTOT);
    scatter1<<<2 * GA, 256, 0, stream>>>(dst, src, gh1, sbuf, NEDGES);

    // ---- pass 2 (high byte, stable) ----
    hist2<<<2 * SCB / 4, 256, 0, stream>>>(sbuf, gh2, NEDGES);
    scan_partial<<<GH2TOT / 256, 256, 0, stream>>>((const int*)gh2, scanned, partials, GH2TOT);
    scan_offs<<<1, 256, 0, stream>>>(partials, offs, GH2TOT / 256);
    scan_final_ex<<<GH2TOT / 256, 256, 0, stream>>>(scanned, offs, gh2, GH2TOT);
    scatter2_stable<<<2 * SCB / 4, 256, 0, stream>>>(sbuf, gh2, sorted, NEDGES);

    // ---- row pointers (rs computed inline downstream) ----
    bounds_kernel<<<2 * NBE, 256, 0, stream>>>(sorted, row_ptr, rp_src, NEDGES);

    // ---- layer 1 ----
    gemm_scaled<256, 128, true><<<(NNODES + 63) / 64, 256, 0, stream>>>(x, W1, rp_src, h, NNODES);
    gather1<<<(NNODES + 3) / 4, 256, 0, stream>>>((const u32*)h, row_ptr, sorted, b1, (u32*)h1, NNODES);

    // ---- layer 2 ----
    gemm_scaled<128, 64, false><<<(NNODES + 63) / 64, 256, 0, stream>>>(h1, W2, rp_src, h2, NNODES);
    gather2<<<(NNODES + 7) / 8, 256, 0, stream>>>((const u32*)h2, row_ptr, sorted, b2, Wf, bfv,
                                                  out_logits, out_hidden, NNODES);
}

// Round 8
// 272.881 us; speedup vs baseline: 2.7939x; 1.0560x over previous
//
#include <hip/hip_runtime.h>
#include <hip/hip_bf16.h>
#include <cstdint>
#include <cstddef>

#define NNODES 50000
#define NEDGES 800000
#define NBLK   ((NNODES + 255) / 256)     // 196
// pass 1 (low byte of key, unstable OK): 256-thread blocks over 8192-element chunks
#define CHUNK1 8192
#define GA     98                          // ceil(NEDGES/CHUNK1)
#define GHHALF (256 * GA)                  // 25088
#define GHTOT  (2 * GHHALF)                // 50176 = 196*256
// pass 2 (high byte, STABLE): 1 wave per 2000-element chunk
#define SCB    400                         // chunks per dataset; 400*2000 = 800000 exact
#define C2     2000
#define GH2HALF (256 * SCB)                // 102400
#define GH2TOT  (2 * GH2HALF)              // 204800 = 800*256
#define NBE    ((NEDGES + 255) / 256)      // 3125

typedef unsigned short u16;
typedef unsigned int u32;
typedef short bfrag8 __attribute__((ext_vector_type(8)));
typedef float f32x4 __attribute__((ext_vector_type(4)));

__device__ __forceinline__ u16 f2bf(float f) {
    union { float f; uint32_t i; } v; v.f = f;
    uint32_t r = (v.i + 0x7FFFu + ((v.i >> 16) & 1u)) >> 16;
    return (u16)r;
}
__device__ __forceinline__ float bflo(u32 p) { union { uint32_t i; float f; } v; v.i = p << 16; return v.f; }
__device__ __forceinline__ float bfhi(u32 p) { union { uint32_t i; float f; } v; v.i = p & 0xFFFF0000u; return v.f; }

// ============ radix sort of packed u32 elements (unchanged, verified r6-7) ============
// element: dataset A (CSR) = (dst<<16)|src ; dataset B (out-degree) = src<<16.
// Sort key = element>>16. Joint layout [A | B]; sorted array IS the CSR.

__global__ __launch_bounds__(256) void hist1(const int* __restrict__ dst, const int* __restrict__ src,
                                             u32* __restrict__ gh, int nE) {
    __shared__ u32 hist[256];
    hist[threadIdx.x] = 0;
    __syncthreads();
    int b = blockIdx.x;
    int dsB = (b >= GA);
    int bb = dsB ? b - GA : b;
    int beg = bb * CHUNK1, end = min(beg + CHUNK1, nE);
    for (int i = beg + threadIdx.x; i < end; i += 256) {
        u32 d = dsB ? ((u32)src[i] & 255u) : ((u32)dst[i] & 255u);
        atomicAdd(&hist[d], 1);
    }
    __syncthreads();
    gh[dsB * GHHALF + threadIdx.x * GA + bb] = hist[threadIdx.x];
}

__global__ __launch_bounds__(256) void scatter1(const int* __restrict__ dst, const int* __restrict__ src,
                                                const u32* __restrict__ ex, u32* __restrict__ sbuf, int nE) {
    __shared__ u32 base[256];
    __shared__ u32 lh[256];
    int b = blockIdx.x;
    int dsB = (b >= GA);
    int bb = dsB ? b - GA : b;
    base[threadIdx.x] = ex[dsB * GHHALF + threadIdx.x * GA + bb];
    lh[threadIdx.x] = 0;
    __syncthreads();
    int beg = bb * CHUNK1, end = min(beg + CHUNK1, nE);
    for (int i = beg + threadIdx.x; i < end; i += 256) {
        u32 el = dsB ? ((u32)src[i] << 16) : (((u32)dst[i] << 16) | (u32)src[i]);
        u32 d = (el >> 16) & 255u;
        u32 r = atomicAdd(&lh[d], 1);
        sbuf[base[d] + r] = el;
    }
}

__global__ __launch_bounds__(256) void hist2(const u32* __restrict__ sbuf, u32* __restrict__ gh2, int nE) {
    __shared__ u32 hist[4][256];
    int wave = threadIdx.x >> 6, lane = threadIdx.x & 63;
    int cg = blockIdx.x * 4 + wave;
    int dsB = (cg >= SCB);
    int cc = dsB ? cg - SCB : cg;
    for (int j = lane; j < 256; j += 64) hist[wave][j] = 0;
    __syncthreads();
    const u32* in = sbuf + (size_t)dsB * nE;
    int beg = cc * C2, end = min(beg + C2, nE);
    for (int i = beg + lane; i < end; i += 64)
        atomicAdd(&hist[wave][in[i] >> 24], 1);
    __syncthreads();
    for (int j = lane; j < 256; j += 64)
        gh2[dsB * GH2HALF + j * SCB + cc] = hist[wave][j];
}

__global__ __launch_bounds__(256) void scatter2_stable(const u32* __restrict__ sbuf, const u32* __restrict__ ex,
                                                       u32* __restrict__ sorted, int nE) {
    __shared__ u32 run[4][256];
    int wave = threadIdx.x >> 6, lane = threadIdx.x & 63;
    int cg = blockIdx.x * 4 + wave;
    int dsB = (cg >= SCB);
    int cc = dsB ? cg - SCB : cg;
    for (int j = lane; j < 256; j += 64) run[wave][j] = ex[dsB * GH2HALF + j * SCB + cc];
    __syncthreads();
    const u32* in = sbuf + (size_t)dsB * nE;
    int beg = cc * C2, end = min(beg + C2, nE);
    for (int i0 = beg; i0 < end; i0 += 64) {
        int i = i0 + lane;
        int active = (i < end);
        u32 el = active ? in[i] : 0;
        u32 d = el >> 24;
        unsigned long long m = __ballot(active);
        #pragma unroll
        for (int b = 0; b < 8; b++) {
            unsigned long long bb_ = __ballot(active && ((d >> b) & 1));
            m &= ((d >> b) & 1) ? bb_ : ~bb_;
        }
        if (active) {
            int lanerank = __popcll(m & ((1ull << lane) - 1ull));
            int leader = __ffsll((long long)m) - 1;
            u32 base = 0;
            if (lane == leader) base = atomicAdd(&run[wave][d], (u32)__popcll(m));
            base = (u32)__shfl((int)base, leader, 64);
            sorted[base + (u32)lanerank] = el;
        }
    }
}

__global__ __launch_bounds__(256) void scan_partial(const int* __restrict__ cnt, int* __restrict__ scanned,
                                                    int* __restrict__ partials, int n) {
    __shared__ int sd[256];
    int t = threadIdx.x;
    int i = blockIdx.x * 256 + t;
    int v = (i < n) ? cnt[i] : 0;
    sd[t] = v;
    __syncthreads();
    #pragma unroll
    for (int o = 1; o < 256; o <<= 1) {
        int add = (t >= o) ? sd[t - o] : 0;
        __syncthreads();
        sd[t] += add;
        __syncthreads();
    }
    if (i < n) scanned[i] = sd[t];
    if (t == 255) partials[blockIdx.x] = sd[255];
}

__global__ __launch_bounds__(256) void scan_offs(const int* __restrict__ partials, int* __restrict__ offs, int nb) {
    __shared__ int sd[256];
    int t = threadIdx.x;
    int v[4]; int s = 0;
    #pragma unroll
    for (int j = 0; j < 4; j++) { int idx = t * 4 + j; v[j] = (idx < nb) ? partials[idx] : 0; s += v[j]; }
    sd[t] = s;
    __syncthreads();
    #pragma unroll
    for (int o = 1; o < 256; o <<= 1) {
        int add = (t >= o) ? sd[t - o] : 0;
        __syncthreads();
        sd[t] += add;
        __syncthreads();
    }
    int base = sd[t] - s;
    #pragma unroll
    for (int j = 0; j < 4; j++) { int idx = t * 4 + j; if (idx < nb) offs[idx] = base; base += v[j]; }
}

__global__ __launch_bounds__(256) void scan_final_ex(const int* __restrict__ scanned, const int* __restrict__ offs,
                                                     u32* __restrict__ gh, int n) {
    int i = blockIdx.x * 256 + threadIdx.x;
    if (i < n) {
        int incl = scanned[i] + offs[blockIdx.x];
        gh[i] = (u32)(incl - (int)gh[i]);
    }
}

__global__ __launch_bounds__(256) void bounds_kernel(const u32* __restrict__ sorted,
                                                     int* __restrict__ rp, int* __restrict__ rps, int nE) {
    int dsB = (blockIdx.x >= NBE);
    int e = (blockIdx.x - (dsB ? NBE : 0)) * 256 + threadIdx.x;
    if (e >= nE) return;
    const u32* ks = sorted + (size_t)dsB * nE;
    int* out = dsB ? rps : rp;
    int k = (int)(ks[e] >> 16);
    int kp = e ? (int)(ks[e - 1] >> 16) : -1;
    if (k != kp)
        for (int n = kp + 1; n <= k; n++) out[n] = e;
    if (e == nE - 1)
        for (int n = k + 1; n <= NNODES; n++) out[n] = nE;
}

// ============ dense compute ============

// one-time W conversion: fp32 row-major -> bf16 packed MFMA B-fragment layout
// Wpack[k/8][n][k%8]; a lane's B-frag for (kq2, col) is 16 contiguous bytes.
__global__ __launch_bounds__(256) void prep_w(const float* __restrict__ W1, const float* __restrict__ W2,
                                              u16* __restrict__ P1, u16* __restrict__ P2) {
    int i = blockIdx.x * 256 + threadIdx.x;
    if (i < 256 * 128) {
        int k = i >> 7, n = i & 127;
        P1[((((k >> 3) << 7) + n) << 3) | (k & 7)] = f2bf(W1[i]);
    }
    if (i < 128 * 64) {
        int k = i >> 6, n = i & 63;
        P2[((((k >> 3) << 6) + n) << 3) | (k & 7)] = f2bf(W2[i]);
    }
}

// out_bf16[M,N] = bf16round((A[M,K] @ W[K,N]) * rsqrt(max(deg_out,1)))
// No LDS: B-frags read straight from packed global (L2-hot, coalesced 256B runs).
template <int K, int N, bool AF32>
__global__ __launch_bounds__(256) void gemm_scaled(const void* __restrict__ A_, const u16* __restrict__ Wp,
                                                   const int* __restrict__ rp_src, u16* __restrict__ out, int M) {
    const int lane = threadIdx.x & 63;
    const int wave = threadIdx.x >> 6;
    const int m = lane & 15;
    const int q = lane >> 4;
    const int row0 = blockIdx.x * 64 + wave * 16;

    int rowa = row0 + m; if (rowa > M - 1) rowa = M - 1;   // clamp OOB loads

    constexpr int NT = N / 16;
    f32x4 acc[NT];
    #pragma unroll
    for (int t = 0; t < NT; t++) acc[t] = (f32x4){0.f, 0.f, 0.f, 0.f};

    #pragma unroll
    for (int kc = 0; kc < K; kc += 32) {
        bfrag8 af;
        if constexpr (AF32) {
            const float* ap = (const float*)A_ + (size_t)rowa * K + q * 8 + kc;
            const float4 x0 = *(const float4*)(ap);
            const float4 x1 = *(const float4*)(ap + 4);
            af[0] = (short)f2bf(x0.x); af[1] = (short)f2bf(x0.y);
            af[2] = (short)f2bf(x0.z); af[3] = (short)f2bf(x0.w);
            af[4] = (short)f2bf(x1.x); af[5] = (short)f2bf(x1.y);
            af[6] = (short)f2bf(x1.z); af[7] = (short)f2bf(x1.w);
        } else {
            const u16* ap = (const u16*)A_ + (size_t)rowa * K + q * 8 + kc;
            af = *(const bfrag8*)ap;
        }
        const u16* bbase = Wp + ((size_t)(((kc >> 3) + q) * N) + m) * 8;
        #pragma unroll
        for (int t = 0; t < NT; t++) {
            bfrag8 bf_ = *(const bfrag8*)(bbase + t * 128);   // t*16 cols * 8
            acc[t] = __builtin_amdgcn_mfma_f32_16x16x32_bf16(af, bf_, acc[t], 0, 0, 0);
        }
    }
    // C/D: col = lane&15, row = (lane>>4)*4 + r
    #pragma unroll
    for (int r = 0; r < 4; r++) {
        int gr = row0 + q * 4 + r;
        if (gr < M) {
            int dO = rp_src[gr + 1] - rp_src[gr]; if (dO < 1) dO = 1;
            float s = rsqrtf((float)dO);
            #pragma unroll
            for (int t = 0; t < NT; t++)
                out[(size_t)gr * N + t * 16 + m] = f2bf(acc[t][r] * s);
        }
    }
}

// ---- layer-1 gather + epilogue: unroll-4 MLP; col = sorted[e]&0xFFFF ----
__global__ __launch_bounds__(256) void gather1(const u32* __restrict__ h, const int* __restrict__ row_ptr,
                                               const u32* __restrict__ sorted, const float* __restrict__ b1,
                                               u32* __restrict__ h1out, int nNodes) {
    int lane = threadIdx.x & 63;
    int node = blockIdx.x * 4 + (threadIdx.x >> 6);
    if (node >= nNodes) return;
    int beg = row_ptr[node], end = row_ptr[node + 1];
    float a0 = 0.f, a1 = 0.f;
    int e = beg;
    for (; e + 3 < end; e += 4) {
        int s0 = (int)(sorted[e + 0] & 0xFFFFu);
        int s1 = (int)(sorted[e + 1] & 0xFFFFu);
        int s2 = (int)(sorted[e + 2] & 0xFFFFu);
        int s3 = (int)(sorted[e + 3] & 0xFFFFu);
        u32 p0 = h[(size_t)s0 * 64 + lane];
        u32 p1 = h[(size_t)s1 * 64 + lane];
        u32 p2 = h[(size_t)s2 * 64 + lane];
        u32 p3 = h[(size_t)s3 * 64 + lane];
        a0 += (bflo(p0) + bflo(p1)) + (bflo(p2) + bflo(p3));
        a1 += (bfhi(p0) + bfhi(p1)) + (bfhi(p2) + bfhi(p3));
    }
    for (; e < end; e++) {
        u32 p = h[(size_t)(sorted[e] & 0xFFFFu) * 64 + lane];
        a0 += bflo(p);
        a1 += bfhi(p);
    }
    int dI = end - beg; if (dI < 1) dI = 1;
    float r = rsqrtf((float)dI);
    float v0 = fmaxf(a0 * r + b1[2 * lane + 0], 0.f);
    float v1 = fmaxf(a1 * r + b1[2 * lane + 1], 0.f);
    h1out[(size_t)node * 64 + lane] = ((u32)f2bf(v1) << 16) | f2bf(v0);
}

// ---- layer-2 gather + epilogue + final projection: half-wave per node, unroll-4 ----
__global__ __launch_bounds__(256) void gather2(const u32* __restrict__ h2, const int* __restrict__ row_ptr,
                                               const u32* __restrict__ sorted, const float* __restrict__ b2,
                                               const float* __restrict__ Wf, const float* __restrict__ bfv,
                                               float* __restrict__ logits, float* __restrict__ hidden, int nNodes) {
    int lane = threadIdx.x & 63;
    int l = lane & 31;
    int node = blockIdx.x * 8 + (threadIdx.x >> 5);
    if (node >= nNodes) return;
    int beg = row_ptr[node], end = row_ptr[node + 1];
    float a0 = 0.f, a1 = 0.f;
    int e = beg;
    for (; e + 3 < end; e += 4) {
        int s0 = (int)(sorted[e + 0] & 0xFFFFu);
        int s1 = (int)(sorted[e + 1] & 0xFFFFu);
        int s2 = (int)(sorted[e + 2] & 0xFFFFu);
        int s3 = (int)(sorted[e + 3] & 0xFFFFu);
        u32 p0 = h2[(size_t)s0 * 32 + l];
        u32 p1 = h2[(size_t)s1 * 32 + l];
        u32 p2 = h2[(size_t)s2 * 32 + l];
        u32 p3 = h2[(size_t)s3 * 32 + l];
        a0 += (bflo(p0) + bflo(p1)) + (bflo(p2) + bflo(p3));
        a1 += (bfhi(p0) + bfhi(p1)) + (bfhi(p2) + bfhi(p3));
    }
    for (; e < end; e++) {
        u32 p = h2[(size_t)(sorted[e] & 0xFFFFu) * 32 + l];
        a0 += bflo(p);
        a1 += bfhi(p);
    }
    int dI = end - beg; if (dI < 1) dI = 1;
    float r = rsqrtf((float)dI);
    float v0 = a0 * r + b2[2 * l + 0];
    float v1 = a1 * r + b2[2 * l + 1];
    hidden[(size_t)node * 64 + 2 * l + 0] = v0;
    hidden[(size_t)node * 64 + 2 * l + 1] = v1;
    float l0 = v0 * Wf[(2 * l) * 2 + 0] + v1 * Wf[(2 * l + 1) * 2 + 0];
    float l1 = v0 * Wf[(2 * l) * 2 + 1] + v1 * Wf[(2 * l + 1) * 2 + 1];
    #pragma unroll
    for (int off = 16; off > 0; off >>= 1) {
        l0 += __shfl_down(l0, off, 32);
        l1 += __shfl_down(l1, off, 32);
    }
    if (l == 0) {
        logits[(size_t)node * 2 + 0] = l0 + bfv[0];
        logits[(size_t)node * 2 + 1] = l1 + bfv[1];
    }
}

extern "C" void kernel_launch(void* const* d_in, const int* in_sizes, int n_in,
                              void* d_out, int out_size, void* d_ws, size_t ws_size,
                              hipStream_t stream) {
    const float* x   = (const float*)d_in[0];
    const float* W1  = (const float*)d_in[1];
    const float* b1  = (const float*)d_in[2];
    const float* W2  = (const float*)d_in[3];
    const float* b2  = (const float*)d_in[4];
    const float* Wf  = (const float*)d_in[5];
    const float* bfv = (const float*)d_in[6];
    const int* src = (const int*)d_in[7];
    const int* dst = (const int*)d_in[8];

    float* out_logits = (float*)d_out;
    float* out_hidden = (float*)d_out + 2 * NNODES;

    char* ws = (char*)d_ws;
    size_t off = 0;
    auto alloc = [&](size_t bytes) { void* p = ws + off; off += (bytes + 255) & ~(size_t)255; return p; };
    u32*   gh1     = (u32*)alloc(GHTOT * 4);
    u32*   gh2     = (u32*)alloc(GH2TOT * 4);
    int*   scanned = (int*)alloc(GH2TOT * 4);
    int*   partials= (int*)alloc(1024 * 4);
    int*   offs    = (int*)alloc(1024 * 4);
    u32*   sbuf    = (u32*)alloc((size_t)2 * NEDGES * 4);
    u32*   sorted  = (u32*)alloc((size_t)2 * NEDGES * 4);
    int*   row_ptr = (int*)alloc((NNODES + 1) * 4);
    int*   rp_src  = (int*)alloc((NNODES + 1) * 4);
    u16*   Wp1     = (u16*)alloc(256 * 128 * 2);
    u16*   Wp2     = (u16*)alloc(128 * 64 * 2);
    u16*   h       = (u16*)alloc((size_t)NNODES * 128 * 2);
    u16*   h1      = (u16*)alloc((size_t)NNODES * 128 * 2);
    u16*   h2      = (u16*)alloc((size_t)NNODES * 64 * 2);

    // ---- static weight prep (runs every call; ws is re-poisoned) ----
    prep_w<<<128, 256, 0, stream>>>(W1, W2, Wp1, Wp2);

    // ---- pass 1 (low byte of node id, unstable) ----
    hist1<<<2 * GA, 256, 0, stream>>>(dst, src, gh1, NEDGES);
    scan_partial<<<GHTOT / 256, 256, 0, stream>>>((const int*)gh1, scanned, partials, GHTOT);
    scan_offs<<<1, 256, 0, stream>>>(partials, offs, GHTOT / 256);
    scan_final_ex<<<GHTOT / 256, 256, 0, stream>>>(scanned, offs, gh1, GHTOT);
    scatter1<<<2 * GA, 256, 0, stream>>>(dst, src, gh1, sbuf, NEDGES);

    // ---- pass 2 (high byte, stable) ----
    hist2<<<2 * SCB / 4, 256, 0, stream>>>(sbuf, gh2, NEDGES);
    scan_partial<<<GH2TOT / 256, 256, 0, stream>>>((const int*)gh2, scanned, partials, GH2TOT);
    scan_offs<<<1, 256, 0, stream>>>(partials, offs, GH2TOT / 256);
    scan_final_ex<<<GH2TOT / 256, 256, 0, stream>>>(scanned, offs, gh2, GH2TOT);
    scatter2_stable<<<2 * SCB / 4, 256, 0, stream>>>(sbuf, gh2, sorted, NEDGES);

    // ---- row pointers ----
    bounds_kernel<<<2 * NBE, 256, 0, stream>>>(sorted, row_ptr, rp_src, NEDGES);

    // ---- layer 1 ----
    gemm_scaled<256, 128, true><<<(NNODES + 63) / 64, 256, 0, stream>>>(x, Wp1, rp_src, h, NNODES);
    gather1<<<(NNODES + 3) / 4, 256, 0, stream>>>((const u32*)h, row_ptr, sorted, b1, (u32*)h1, NNODES);

    // ---- layer 2 ----
    gemm_scaled<128, 64, false><<<(NNODES + 63) / 64, 256, 0, stream>>>(h1, Wp2, rp_src, h2, NNODES);
    gather2<<<(NNODES + 7) / 8, 256, 0, stream>>>((const u32*)h2, row_ptr, sorted, b2, Wf, bfv,
                                                  out_logits, out_hidden, NNODES);
}

// Round 9
// 255.141 us; speedup vs baseline: 2.9882x; 1.0695x over previous
//
#include <hip/hip_runtime.h>
#include <hip/hip_bf16.h>
#include <cstdint>
#include <cstddef>

#define NNODES 50000
#define NEDGES 800000
// pass 1 (low byte, unstable OK): 256-thread blocks over 4096-element chunks
#define CHUNK1 4096
#define GA1    196                         // ceil(NEDGES/CHUNK1)
#define GH1TOT (256 * GA1)                 // 50176
// pass 2 (high byte, STABLE): 1 wave per 1000-element chunk
#define C2     1000
#define SCB    800                         // 800*1000 = 800000 exact
#define GH2TOT (256 * SCB)                 // 204800
#define NBE    ((NEDGES + 255) / 256)      // 3125
// out-degree histogram
#define DHB    200
#define DHC    4000                        // 200*4000 = 800000 exact

typedef unsigned short u16;
typedef unsigned int u32;
typedef short bfrag8 __attribute__((ext_vector_type(8)));
typedef float f32x4 __attribute__((ext_vector_type(4)));

__device__ __forceinline__ u16 f2bf(float f) {
    union { float f; uint32_t i; } v; v.f = f;
    uint32_t r = (v.i + 0x7FFFu + ((v.i >> 16) & 1u)) >> 16;
    return (u16)r;
}
__device__ __forceinline__ float bflo(u32 p) { union { uint32_t i; float f; } v; v.i = p << 16; return v.f; }
__device__ __forceinline__ float bfhi(u32 p) { union { uint32_t i; float f; } v; v.i = p & 0xFFFF0000u; return v.f; }

// ============ out-degree: LDS-privatized histogram (no global atomics) ============
__global__ __launch_bounds__(256) void deg_hist(const int* __restrict__ src, u32* __restrict__ histg, int nE) {
    __shared__ u32 hh[NNODES / 2];         // 50000 u16 counters packed in 25000 u32 (100 KB)
    for (int j = threadIdx.x; j < NNODES / 2; j += 256) hh[j] = 0;
    __syncthreads();
    int beg = blockIdx.x * DHC, end = min(beg + DHC, nE);
    for (int i = beg + threadIdx.x; i < end; i += 256) {
        u32 n = (u32)src[i];
        atomicAdd(&hh[n >> 1], 1u << ((n & 1) * 16));   // per-block count < 65536: no overflow
    }
    __syncthreads();
    u32* out = histg + (size_t)blockIdx.x * (NNODES / 2);
    for (int j = threadIdx.x; j < NNODES / 2; j += 256) out[j] = hh[j];
}

__global__ __launch_bounds__(256) void deg_reduce(const u16* __restrict__ histg, int* __restrict__ deg, int n) {
    int i = blockIdx.x * 256 + threadIdx.x;
    if (i >= n) return;
    int s = 0;
    #pragma unroll 4
    for (int b = 0; b < DHB; b++) s += histg[(size_t)b * NNODES + i];
    deg[i] = s;
}

// ============ radix sort (A only): edges packed (dst<<16)|src, key = dst ============

__global__ __launch_bounds__(256) void hist1(const int* __restrict__ dst, u32* __restrict__ gh, int nE) {
    __shared__ u32 hist[256];
    hist[threadIdx.x] = 0;
    __syncthreads();
    int beg = blockIdx.x * CHUNK1, end = min(beg + CHUNK1, nE);
    for (int i = beg + threadIdx.x; i < end; i += 256)
        atomicAdd(&hist[(u32)dst[i] & 255u], 1);
    __syncthreads();
    gh[threadIdx.x * GA1 + blockIdx.x] = hist[threadIdx.x];
}

// exclusive base computed inline: scanned(incl) + blockoffs - count
__global__ __launch_bounds__(256) void scatter1(const int* __restrict__ dst, const int* __restrict__ src,
                                                const u32* __restrict__ gh, const int* __restrict__ scanned,
                                                const int* __restrict__ offs, u32* __restrict__ sbuf, int nE) {
    __shared__ u32 base[256];
    __shared__ u32 lh[256];
    int idx = threadIdx.x * GA1 + blockIdx.x;
    base[threadIdx.x] = (u32)(scanned[idx] + offs[idx >> 8] - (int)gh[idx]);
    lh[threadIdx.x] = 0;
    __syncthreads();
    int beg = blockIdx.x * CHUNK1, end = min(beg + CHUNK1, nE);
    for (int i = beg + threadIdx.x; i < end; i += 256) {
        u32 el = ((u32)dst[i] << 16) | (u32)src[i];
        u32 d = (el >> 16) & 255u;
        u32 r = atomicAdd(&lh[d], 1);
        sbuf[base[d] + r] = el;
    }
}

__global__ __launch_bounds__(256) void hist2(const u32* __restrict__ sbuf, u32* __restrict__ gh2, int nE) {
    __shared__ u32 hist[4][256];
    int wave = threadIdx.x >> 6, lane = threadIdx.x & 63;
    int cg = blockIdx.x * 4 + wave;        // 0..SCB-1
    for (int j = lane; j < 256; j += 64) hist[wave][j] = 0;
    __syncthreads();
    int beg = cg * C2, end = min(beg + C2, nE);
    for (int i = beg + lane; i < end; i += 64)
        atomicAdd(&hist[wave][sbuf[i] >> 24], 1);
    __syncthreads();
    for (int j = lane; j < 256; j += 64)
        gh2[j * SCB + cg] = hist[wave][j];
}

// STABLE: ballot-match digit groups, lane-order rank, leader bumps per-wave LDS counter
__global__ __launch_bounds__(256) void scatter2_stable(const u32* __restrict__ sbuf, const u32* __restrict__ gh2,
                                                       const int* __restrict__ scanned, const int* __restrict__ offs,
                                                       u32* __restrict__ sorted, int nE) {
    __shared__ u32 run[4][256];
    int wave = threadIdx.x >> 6, lane = threadIdx.x & 63;
    int cg = blockIdx.x * 4 + wave;
    for (int j = lane; j < 256; j += 64) {
        int idx = j * SCB + cg;
        run[wave][j] = (u32)(scanned[idx] + offs[idx >> 8] - (int)gh2[idx]);
    }
    __syncthreads();
    int beg = cg * C2, end = min(beg + C2, nE);
    for (int i0 = beg; i0 < end; i0 += 64) {
        int i = i0 + lane;
        int active = (i < end);
        u32 el = active ? sbuf[i] : 0;
        u32 d = el >> 24;
        unsigned long long m = __ballot(active);
        #pragma unroll
        for (int b = 0; b < 8; b++) {
            unsigned long long bb_ = __ballot(active && ((d >> b) & 1));
            m &= ((d >> b) & 1) ? bb_ : ~bb_;
        }
        if (active) {
            int lanerank = __popcll(m & ((1ull << lane) - 1ull));
            int leader = __ffsll((long long)m) - 1;
            u32 base = 0;
            if (lane == leader) base = atomicAdd(&run[wave][d], (u32)__popcll(m));
            base = (u32)__shfl((int)base, leader, 64);
            sorted[base + (u32)lanerank] = el;
        }
    }
}

__global__ __launch_bounds__(256) void scan_partial(const int* __restrict__ cnt, int* __restrict__ scanned,
                                                    int* __restrict__ partials, int n) {
    __shared__ int sd[256];
    int t = threadIdx.x;
    int i = blockIdx.x * 256 + t;
    int v = (i < n) ? cnt[i] : 0;
    sd[t] = v;
    __syncthreads();
    #pragma unroll
    for (int o = 1; o < 256; o <<= 1) {
        int add = (t >= o) ? sd[t - o] : 0;
        __syncthreads();
        sd[t] += add;
        __syncthreads();
    }
    if (i < n) scanned[i] = sd[t];
    if (t == 255) partials[blockIdx.x] = sd[255];
}

__global__ __launch_bounds__(256) void scan_offs(const int* __restrict__ partials, int* __restrict__ offs, int nb) {
    __shared__ int sd[256];
    int t = threadIdx.x;
    int v[4]; int s = 0;
    #pragma unroll
    for (int j = 0; j < 4; j++) { int idx = t * 4 + j; v[j] = (idx < nb) ? partials[idx] : 0; s += v[j]; }
    sd[t] = s;
    __syncthreads();
    #pragma unroll
    for (int o = 1; o < 256; o <<= 1) {
        int add = (t >= o) ? sd[t - o] : 0;
        __syncthreads();
        sd[t] += add;
        __syncthreads();
    }
    int base = sd[t] - s;
    #pragma unroll
    for (int j = 0; j < 4; j++) { int idx = t * 4 + j; if (idx < nb) offs[idx] = base; base += v[j]; }
}

__global__ __launch_bounds__(256) void bounds_kernel(const u32* __restrict__ sorted, int* __restrict__ rp, int nE) {
    int e = blockIdx.x * 256 + threadIdx.x;
    if (e >= nE) return;
    int k = (int)(sorted[e] >> 16);
    int kp = e ? (int)(sorted[e - 1] >> 16) : -1;
    if (k != kp)
        for (int n = kp + 1; n <= k; n++) rp[n] = e;
    if (e == nE - 1)
        for (int n = k + 1; n <= NNODES; n++) rp[n] = nE;
}

// ============ dense compute ============

// one-time W conversion: fp32 row-major -> bf16 packed MFMA B-fragment layout Wpack[k/8][n][k%8]
__global__ __launch_bounds__(256) void prep_w(const float* __restrict__ W1, const float* __restrict__ W2,
                                              u16* __restrict__ P1, u16* __restrict__ P2) {
    int i = blockIdx.x * 256 + threadIdx.x;
    if (i < 256 * 128) {
        int k = i >> 7, n = i & 127;
        P1[((((k >> 3) << 7) + n) << 3) | (k & 7)] = f2bf(W1[i]);
    }
    if (i < 128 * 64) {
        int k = i >> 6, n = i & 63;
        P2[((((k >> 3) << 6) + n) << 3) | (k & 7)] = f2bf(W2[i]);
    }
}

// out_bf16[M,N] = bf16round((A[M,K] @ W[K,N]) * rsqrt(max(deg[row],1)))
// No LDS: B-frags straight from packed global (L2-hot, coalesced).
template <int K, int N, bool AF32>
__global__ __launch_bounds__(256) void gemm_scaled(const void* __restrict__ A_, const u16* __restrict__ Wp,
                                                   const int* __restrict__ deg, u16* __restrict__ out, int M) {
    const int lane = threadIdx.x & 63;
    const int wave = threadIdx.x >> 6;
    const int m = lane & 15;
    const int q = lane >> 4;
    const int row0 = blockIdx.x * 64 + wave * 16;

    int rowa = row0 + m; if (rowa > M - 1) rowa = M - 1;

    constexpr int NT = N / 16;
    f32x4 acc[NT];
    #pragma unroll
    for (int t = 0; t < NT; t++) acc[t] = (f32x4){0.f, 0.f, 0.f, 0.f};

    #pragma unroll
    for (int kc = 0; kc < K; kc += 32) {
        bfrag8 af;
        if constexpr (AF32) {
            const float* ap = (const float*)A_ + (size_t)rowa * K + q * 8 + kc;
            const float4 x0 = *(const float4*)(ap);
            const float4 x1 = *(const float4*)(ap + 4);
            af[0] = (short)f2bf(x0.x); af[1] = (short)f2bf(x0.y);
            af[2] = (short)f2bf(x0.z); af[3] = (short)f2bf(x0.w);
            af[4] = (short)f2bf(x1.x); af[5] = (short)f2bf(x1.y);
            af[6] = (short)f2bf(x1.z); af[7] = (short)f2bf(x1.w);
        } else {
            const u16* ap = (const u16*)A_ + (size_t)rowa * K + q * 8 + kc;
            af = *(const bfrag8*)ap;
        }
        const u16* bbase = Wp + ((size_t)(((kc >> 3) + q) * N) + m) * 8;
        #pragma unroll
        for (int t = 0; t < NT; t++) {
            bfrag8 bf_ = *(const bfrag8*)(bbase + t * 128);
            acc[t] = __builtin_amdgcn_mfma_f32_16x16x32_bf16(af, bf_, acc[t], 0, 0, 0);
        }
    }
    #pragma unroll
    for (int r = 0; r < 4; r++) {
        int gr = row0 + q * 4 + r;
        if (gr < M) {
            int dO = deg[gr]; if (dO < 1) dO = 1;
            float s = rsqrtf((float)dO);
            #pragma unroll
            for (int t = 0; t < NT; t++)
                out[(size_t)gr * N + t * 16 + m] = f2bf(acc[t][r] * s);
        }
    }
}

// ---- layer-1 gather + epilogue: wave per node, unroll-8 MLP ----
__global__ __launch_bounds__(256) void gather1(const u32* __restrict__ h, const int* __restrict__ row_ptr,
                                               const u32* __restrict__ sorted, const float* __restrict__ b1,
                                               u32* __restrict__ h1out, int nNodes) {
    int lane = threadIdx.x & 63;
    int node = blockIdx.x * 4 + (threadIdx.x >> 6);
    if (node >= nNodes) return;
    int beg = row_ptr[node], end = row_ptr[node + 1];
    float a0 = 0.f, a1 = 0.f;
    int e = beg;
    for (; e + 7 < end; e += 8) {
        u32 p0 = h[(size_t)(sorted[e + 0] & 0xFFFFu) * 64 + lane];
        u32 p1 = h[(size_t)(sorted[e + 1] & 0xFFFFu) * 64 + lane];
        u32 p2 = h[(size_t)(sorted[e + 2] & 0xFFFFu) * 64 + lane];
        u32 p3 = h[(size_t)(sorted[e + 3] & 0xFFFFu) * 64 + lane];
        u32 p4 = h[(size_t)(sorted[e + 4] & 0xFFFFu) * 64 + lane];
        u32 p5 = h[(size_t)(sorted[e + 5] & 0xFFFFu) * 64 + lane];
        u32 p6 = h[(size_t)(sorted[e + 6] & 0xFFFFu) * 64 + lane];
        u32 p7 = h[(size_t)(sorted[e + 7] & 0xFFFFu) * 64 + lane];
        a0 += ((bflo(p0) + bflo(p1)) + (bflo(p2) + bflo(p3))) + ((bflo(p4) + bflo(p5)) + (bflo(p6) + bflo(p7)));
        a1 += ((bfhi(p0) + bfhi(p1)) + (bfhi(p2) + bfhi(p3))) + ((bfhi(p4) + bfhi(p5)) + (bfhi(p6) + bfhi(p7)));
    }
    for (; e + 3 < end; e += 4) {
        u32 p0 = h[(size_t)(sorted[e + 0] & 0xFFFFu) * 64 + lane];
        u32 p1 = h[(size_t)(sorted[e + 1] & 0xFFFFu) * 64 + lane];
        u32 p2 = h[(size_t)(sorted[e + 2] & 0xFFFFu) * 64 + lane];
        u32 p3 = h[(size_t)(sorted[e + 3] & 0xFFFFu) * 64 + lane];
        a0 += (bflo(p0) + bflo(p1)) + (bflo(p2) + bflo(p3));
        a1 += (bfhi(p0) + bfhi(p1)) + (bfhi(p2) + bfhi(p3));
    }
    for (; e < end; e++) {
        u32 p = h[(size_t)(sorted[e] & 0xFFFFu) * 64 + lane];
        a0 += bflo(p);
        a1 += bfhi(p);
    }
    int dI = end - beg; if (dI < 1) dI = 1;
    float r = rsqrtf((float)dI);
    float v0 = fmaxf(a0 * r + b1[2 * lane + 0], 0.f);
    float v1 = fmaxf(a1 * r + b1[2 * lane + 1], 0.f);
    h1out[(size_t)node * 64 + lane] = ((u32)f2bf(v1) << 16) | f2bf(v0);
}

// ---- layer-2 gather + epilogue + final projection: half-wave per node, unroll-8 ----
__global__ __launch_bounds__(256) void gather2(const u32* __restrict__ h2, const int* __restrict__ row_ptr,
                                               const u32* __restrict__ sorted, const float* __restrict__ b2,
                                               const float* __restrict__ Wf, const float* __restrict__ bfv,
                                               float* __restrict__ logits, float* __restrict__ hidden, int nNodes) {
    int lane = threadIdx.x & 63;
    int l = lane & 31;
    int node = blockIdx.x * 8 + (threadIdx.x >> 5);
    if (node >= nNodes) return;
    int beg = row_ptr[node], end = row_ptr[node + 1];
    float a0 = 0.f, a1 = 0.f;
    int e = beg;
    for (; e + 7 < end; e += 8) {
        u32 p0 = h2[(size_t)(sorted[e + 0] & 0xFFFFu) * 32 + l];
        u32 p1 = h2[(size_t)(sorted[e + 1] & 0xFFFFu) * 32 + l];
        u32 p2 = h2[(size_t)(sorted[e + 2] & 0xFFFFu) * 32 + l];
        u32 p3 = h2[(size_t)(sorted[e + 3] & 0xFFFFu) * 32 + l];
        u32 p4 = h2[(size_t)(sorted[e + 4] & 0xFFFFu) * 32 + l];
        u32 p5 = h2[(size_t)(sorted[e + 5] & 0xFFFFu) * 32 + l];
        u32 p6 = h2[(size_t)(sorted[e + 6] & 0xFFFFu) * 32 + l];
        u32 p7 = h2[(size_t)(sorted[e + 7] & 0xFFFFu) * 32 + l];
        a0 += ((bflo(p0) + bflo(p1)) + (bflo(p2) + bflo(p3))) + ((bflo(p4) + bflo(p5)) + (bflo(p6) + bflo(p7)));
        a1 += ((bfhi(p0) + bfhi(p1)) + (bfhi(p2) + bfhi(p3))) + ((bfhi(p4) + bfhi(p5)) + (bfhi(p6) + bfhi(p7)));
    }
    for (; e + 3 < end; e += 4) {
        u32 p0 = h2[(size_t)(sorted[e + 0] & 0xFFFFu) * 32 + l];
        u32 p1 = h2[(size_t)(sorted[e + 1] & 0xFFFFu) * 32 + l];
        u32 p2 = h2[(size_t)(sorted[e + 2] & 0xFFFFu) * 32 + l];
        u32 p3 = h2[(size_t)(sorted[e + 3] & 0xFFFFu) * 32 + l];
        a0 += (bflo(p0) + bflo(p1)) + (bflo(p2) + bflo(p3));
        a1 += (bfhi(p0) + bfhi(p1)) + (bfhi(p2) + bfhi(p3));
    }
    for (; e < end; e++) {
        u32 p = h2[(size_t)(sorted[e] & 0xFFFFu) * 32 + l];
        a0 += bflo(p);
        a1 += bfhi(p);
    }
    int dI = end - beg; if (dI < 1) dI = 1;
    float r = rsqrtf((float)dI);
    float v0 = a0 * r + b2[2 * l + 0];
    float v1 = a1 * r + b2[2 * l + 1];
    hidden[(size_t)node * 64 + 2 * l + 0] = v0;
    hidden[(size_t)node * 64 + 2 * l + 1] = v1;
    float l0 = v0 * Wf[(2 * l) * 2 + 0] + v1 * Wf[(2 * l + 1) * 2 + 0];
    float l1 = v0 * Wf[(2 * l) * 2 + 1] + v1 * Wf[(2 * l + 1) * 2 + 1];
    #pragma unroll
    for (int off = 16; off > 0; off >>= 1) {
        l0 += __shfl_down(l0, off, 32);
        l1 += __shfl_down(l1, off, 32);
    }
    if (l == 0) {
        logits[(size_t)node * 2 + 0] = l0 + bfv[0];
        logits[(size_t)node * 2 + 1] = l1 + bfv[1];
    }
}

extern "C" void kernel_launch(void* const* d_in, const int* in_sizes, int n_in,
                              void* d_out, int out_size, void* d_ws, size_t ws_size,
                              hipStream_t stream) {
    const float* x   = (const float*)d_in[0];
    const float* W1  = (const float*)d_in[1];
    const float* b1  = (const float*)d_in[2];
    const float* W2  = (const float*)d_in[3];
    const float* b2  = (const float*)d_in[4];
    const float* Wf  = (const float*)d_in[5];
    const float* bfv = (const float*)d_in[6];
    const int* src = (const int*)d_in[7];
    const int* dst = (const int*)d_in[8];

    float* out_logits = (float*)d_out;
    float* out_hidden = (float*)d_out + 2 * NNODES;

    char* ws = (char*)d_ws;
    size_t off = 0;
    auto alloc = [&](size_t bytes) { void* p = ws + off; off += (bytes + 255) & ~(size_t)255; return p; };
    u32*   gh1     = (u32*)alloc(GH1TOT * 4);
    u32*   gh2     = (u32*)alloc(GH2TOT * 4);
    int*   scanned = (int*)alloc(GH2TOT * 4);               // reused by both scans
    int*   partials= (int*)alloc(1024 * 4);
    int*   offs    = (int*)alloc(1024 * 4);
    u32*   sbuf    = (u32*)alloc((size_t)NEDGES * 4);       // pass-1 output
    u32*   sorted  = (u32*)alloc((size_t)NEDGES * 4);       // pass-2 output = CSR
    u32*   histg   = (u32*)alloc((size_t)DHB * (NNODES / 2) * 4);  // per-block degree hists (20 MB)
    int*   deg_out = (int*)alloc(NNODES * 4);
    int*   row_ptr = (int*)alloc((NNODES + 1) * 4);
    u16*   Wp1     = (u16*)alloc(256 * 128 * 2);
    u16*   Wp2     = (u16*)alloc(128 * 64 * 2);
    u16*   h       = (u16*)alloc((size_t)NNODES * 128 * 2);
    u16*   h1      = (u16*)alloc((size_t)NNODES * 128 * 2);
    u16*   h2      = (u16*)alloc((size_t)NNODES * 64 * 2);

    // ---- static weight prep ----
    prep_w<<<128, 256, 0, stream>>>(W1, W2, Wp1, Wp2);

    // ---- out-degree histogram (no sort, no global atomics) ----
    deg_hist<<<DHB, 256, 0, stream>>>(src, histg, NEDGES);
    deg_reduce<<<(NNODES + 255) / 256, 256, 0, stream>>>((const u16*)histg, deg_out, NNODES);

    // ---- sort edges by dst: pass 1 (low byte, unstable) ----
    hist1<<<GA1, 256, 0, stream>>>(dst, gh1, NEDGES);
    scan_partial<<<GH1TOT / 256, 256, 0, stream>>>((const int*)gh1, scanned, partials, GH1TOT);
    scan_offs<<<1, 256, 0, stream>>>(partials, offs, GH1TOT / 256);
    scatter1<<<GA1, 256, 0, stream>>>(dst, src, gh1, scanned, offs, sbuf, NEDGES);

    // ---- pass 2 (high byte, stable) ----
    hist2<<<SCB / 4, 256, 0, stream>>>(sbuf, gh2, NEDGES);
    scan_partial<<<GH2TOT / 256, 256, 0, stream>>>((const int*)gh2, scanned, partials, GH2TOT);
    scan_offs<<<1, 256, 0, stream>>>(partials, offs, GH2TOT / 256);
    scatter2_stable<<<SCB / 4, 256, 0, stream>>>(sbuf, gh2, scanned, offs, sorted, NEDGES);

    // ---- row pointers ----
    bounds_kernel<<<NBE, 256, 0, stream>>>(sorted, row_ptr, NEDGES);

    // ---- layer 1 ----
    gemm_scaled<256, 128, true><<<(NNODES + 63) / 64, 256, 0, stream>>>(x, Wp1, deg_out, h, NNODES);
    gather1<<<(NNODES + 3) / 4, 256, 0, stream>>>((const u32*)h, row_ptr, sorted, b1, (u32*)h1, NNODES);

    // ---- layer 2 ----
    gemm_scaled<128, 64, false><<<(NNODES + 63) / 64, 256, 0, stream>>>(h1, Wp2, deg_out, h2, NNODES);
    gather2<<<(NNODES + 7) / 8, 256, 0, stream>>>((const u32*)h2, row_ptr, sorted, b2, Wf, bfv,
                                                  out_logits, out_hidden, NNODES);
}

// Round 10
// 246.329 us; speedup vs baseline: 3.0951x; 1.0358x over previous
//
#include <hip/hip_runtime.h>
#include <hip/hip_bf16.h>
#include <cstdint>
#include <cstddef>

#define NNODES 50000
#define NEDGES 800000
// degree histogram
#define DHB    100
#define DHC    8000                        // 100*8000 = 800000 exact
// sort pass 1 (low byte, unstable OK)
#define CHUNK1 4096
#define GA1    196                         // ceil(NEDGES/CHUNK1)
#define GH1TOT (256 * GA1)                 // 50176
// sort pass 2 (high byte, STABLE): 1 wave per 1000-element chunk
#define C2     1000
#define SCB    800                         // 800*1000 = 800000 exact
#define GH2TOT (256 * SCB)                 // 204800
#define NBE    ((NEDGES + 255) / 256)      // 3125

typedef unsigned short u16;
typedef unsigned int u32;
typedef short bfrag8 __attribute__((ext_vector_type(8)));
typedef float f32x4 __attribute__((ext_vector_type(4)));

__device__ __forceinline__ u16 f2bf(float f) {
    union { float f; uint32_t i; } v; v.f = f;
    uint32_t r = (v.i + 0x7FFFu + ((v.i >> 16) & 1u)) >> 16;
    return (u16)r;
}
__device__ __forceinline__ float bflo(u32 p) { union { uint32_t i; float f; } v; v.i = p << 16; return v.f; }
__device__ __forceinline__ float bfhi(u32 p) { union { uint32_t i; float f; } v; v.i = p & 0xFFFF0000u; return v.f; }

// ============ launch 1: prep_w + deg_hist + hist1 (independent jobs, blockIdx-ranged) ============
__global__ __launch_bounds__(256) void pre_kernel(const float* __restrict__ W1, const float* __restrict__ W2,
                                                  u16* __restrict__ P1, u16* __restrict__ P2,
                                                  const int* __restrict__ src, const int* __restrict__ dst,
                                                  u32* __restrict__ histg, u32* __restrict__ gh1, int nE) {
    __shared__ u32 hh[NNODES / 2];         // 100 KB (works on gfx950 — proven r9)
    int b = blockIdx.x;
    if (b < DHB) {
        // out-degree histogram: u16 counters packed in u32; per-block count < 65536
        for (int j = threadIdx.x; j < NNODES / 2; j += 256) hh[j] = 0;
        __syncthreads();
        int beg = b * DHC, end = min(beg + DHC, nE);
        for (int i = beg + threadIdx.x; i < end; i += 256) {
            u32 n = (u32)src[i];
            atomicAdd(&hh[n >> 1], 1u << ((n & 1) * 16));
        }
        __syncthreads();
        u32* out = histg + (size_t)b * (NNODES / 2);
        for (int j = threadIdx.x; j < NNODES / 2; j += 256) out[j] = hh[j];
    } else if (b < DHB + GA1) {
        // sort pass-1 histogram (low byte of dst)
        int bb = b - DHB;
        hh[threadIdx.x] = 0;
        __syncthreads();
        int beg = bb * CHUNK1, end = min(beg + CHUNK1, nE);
        for (int i = beg + threadIdx.x; i < end; i += 256)
            atomicAdd(&hh[(u32)dst[i] & 255u], 1);
        __syncthreads();
        gh1[threadIdx.x * GA1 + bb] = hh[threadIdx.x];
    } else {
        // weight prep: fp32 row-major -> bf16 packed B-fragment layout Wpack[k/8][n][k%8]
        int i = (b - DHB - GA1) * 256 + threadIdx.x;
        if (i < 256 * 128) {
            int k = i >> 7, n = i & 127;
            P1[((((k >> 3) << 7) + n) << 3) | (k & 7)] = f2bf(W1[i]);
        }
        if (i < 128 * 64) {
            int k = i >> 6, n = i & 63;
            P2[((((k >> 3) << 6) + n) << 3) | (k & 7)] = f2bf(W2[i]);
        }
    }
}

// ============ launch 2: deg_reduce + per-block inclusive scan of gh1 (grid = 196) ============
__global__ __launch_bounds__(256) void red_scan1(const u16* __restrict__ histg16, int* __restrict__ deg,
                                                 const u32* __restrict__ gh1, int* __restrict__ scanned,
                                                 int* __restrict__ partials) {
    int i = blockIdx.x * 256 + threadIdx.x;
    if (i < NNODES) {
        int s = 0;
        #pragma unroll 4
        for (int b = 0; b < DHB; b++) s += histg16[(size_t)b * NNODES + i];
        deg[i] = s;
    }
    __shared__ int sd[256];
    int t = threadIdx.x;
    int gi = blockIdx.x * 256 + t;          // grid 196 -> gi < 50176 = GH1TOT
    int v = (int)gh1[gi];
    sd[t] = v;
    __syncthreads();
    #pragma unroll
    for (int o = 1; o < 256; o <<= 1) {
        int add = (t >= o) ? sd[t - o] : 0;
        __syncthreads();
        sd[t] += add;
        __syncthreads();
    }
    scanned[gi] = sd[t];
    if (t == 255) partials[blockIdx.x] = sd[255];
}

// ============ launch 3: pass-1 scatter, exclusive base inline (re-scans 196 partials) ============
__global__ __launch_bounds__(256) void scatter1(const int* __restrict__ dst, const int* __restrict__ src,
                                                const u32* __restrict__ gh1, const int* __restrict__ scanned,
                                                const int* __restrict__ partials, u32* __restrict__ sbuf, int nE) {
    __shared__ int sd[256];
    __shared__ int offs_l[256];
    __shared__ u32 base[256];
    __shared__ u32 lh[256];
    int t = threadIdx.x;
    int v = (t < GA1) ? partials[t] : 0;
    sd[t] = v;
    __syncthreads();
    #pragma unroll
    for (int o = 1; o < 256; o <<= 1) {
        int add = (t >= o) ? sd[t - o] : 0;
        __syncthreads();
        sd[t] += add;
        __syncthreads();
    }
    offs_l[t] = sd[t] - v;                  // exclusive block offset
    __syncthreads();
    int idx = t * GA1 + blockIdx.x;
    base[t] = (u32)(scanned[idx] + offs_l[idx >> 8] - (int)gh1[idx]);
    lh[t] = 0;
    __syncthreads();
    int beg = blockIdx.x * CHUNK1, end = min(beg + CHUNK1, nE);
    for (int i = beg + t; i < end; i += 256) {
        u32 el = ((u32)dst[i] << 16) | (u32)src[i];
        u32 d = (el >> 16) & 255u;
        u32 r = atomicAdd(&lh[d], 1);
        sbuf[base[d] + r] = el;
    }
}

// ============ launch 4: pass-2 histogram (wave-private, 4 chunks/block) ============
__global__ __launch_bounds__(256) void hist2(const u32* __restrict__ sbuf, u32* __restrict__ gh2, int nE) {
    __shared__ u32 hist[4][256];
    int wave = threadIdx.x >> 6, lane = threadIdx.x & 63;
    int cg = blockIdx.x * 4 + wave;
    for (int j = lane; j < 256; j += 64) hist[wave][j] = 0;
    __syncthreads();
    int beg = cg * C2, end = min(beg + C2, nE);
    for (int i = beg + lane; i < end; i += 64)
        atomicAdd(&hist[wave][sbuf[i] >> 24], 1);
    __syncthreads();
    for (int j = lane; j < 256; j += 64)
        gh2[j * SCB + cg] = hist[wave][j];
}

// ============ launch 5: per-block inclusive scan of gh2 (grid = 800) ============
__global__ __launch_bounds__(256) void scan2(const u32* __restrict__ gh2, int* __restrict__ scanned,
                                             int* __restrict__ partials) {
    __shared__ int sd[256];
    int t = threadIdx.x;
    int gi = blockIdx.x * 256 + t;
    int v = (int)gh2[gi];
    sd[t] = v;
    __syncthreads();
    #pragma unroll
    for (int o = 1; o < 256; o <<= 1) {
        int add = (t >= o) ? sd[t - o] : 0;
        __syncthreads();
        sd[t] += add;
        __syncthreads();
    }
    scanned[gi] = sd[t];
    if (t == 255) partials[blockIdx.x] = sd[255];
}

// ============ launch 6: pass-2 STABLE scatter, base inline (re-scans 800 partials) ============
__global__ __launch_bounds__(256) void scatter2_stable(const u32* __restrict__ sbuf, const u32* __restrict__ gh2,
                                                       const int* __restrict__ scanned, const int* __restrict__ partials,
                                                       u32* __restrict__ sorted, int nE) {
    __shared__ int sd[256];
    __shared__ int offs_l[800];
    __shared__ u32 run[4][256];
    int t = threadIdx.x;
    int v[4]; int s = 0;
    #pragma unroll
    for (int j = 0; j < 4; j++) { int idx = t * 4 + j; v[j] = (idx < 800) ? partials[idx] : 0; s += v[j]; }
    sd[t] = s;
    __syncthreads();
    #pragma unroll
    for (int o = 1; o < 256; o <<= 1) {
        int add = (t >= o) ? sd[t - o] : 0;
        __syncthreads();
        sd[t] += add;
        __syncthreads();
    }
    int bse = sd[t] - s;
    #pragma unroll
    for (int j = 0; j < 4; j++) { int idx = t * 4 + j; if (idx < 800) offs_l[idx] = bse; bse += v[j]; }
    __syncthreads();
    int wave = t >> 6, lane = t & 63;
    int cg = blockIdx.x * 4 + wave;
    for (int j = lane; j < 256; j += 64) {
        int idx = j * SCB + cg;
        run[wave][j] = (u32)(scanned[idx] + offs_l[idx >> 8] - (int)gh2[idx]);
    }
    __syncthreads();
    int beg = cg * C2, end = min(beg + C2, nE);
    for (int i0 = beg; i0 < end; i0 += 64) {
        int i = i0 + lane;
        int active = (i < end);
        u32 el = active ? sbuf[i] : 0;
        u32 d = el >> 24;
        unsigned long long m = __ballot(active);
        #pragma unroll
        for (int b = 0; b < 8; b++) {
            unsigned long long bb_ = __ballot(active && ((d >> b) & 1));
            m &= ((d >> b) & 1) ? bb_ : ~bb_;
        }
        if (active) {
            int lanerank = __popcll(m & ((1ull << lane) - 1ull));
            int leader = __ffsll((long long)m) - 1;
            u32 base = 0;
            if (lane == leader) base = atomicAdd(&run[wave][d], (u32)__popcll(m));
            base = (u32)__shfl((int)base, leader, 64);
            sorted[base + (u32)lanerank] = el;
        }
    }
}

// ============ launch 7: boundary detection -> row_ptr ============
__global__ __launch_bounds__(256) void bounds_kernel(const u32* __restrict__ sorted, int* __restrict__ rp, int nE) {
    int e = blockIdx.x * 256 + threadIdx.x;
    if (e >= nE) return;
    int k = (int)(sorted[e] >> 16);
    int kp = e ? (int)(sorted[e - 1] >> 16) : -1;
    if (k != kp)
        for (int n = kp + 1; n <= k; n++) rp[n] = e;
    if (e == nE - 1)
        for (int n = k + 1; n <= NNODES; n++) rp[n] = nE;
}

// ============ dense compute (verified r8/r9) ============

template <int K, int N, bool AF32>
__global__ __launch_bounds__(256) void gemm_scaled(const void* __restrict__ A_, const u16* __restrict__ Wp,
                                                   const int* __restrict__ deg, u16* __restrict__ out, int M) {
    const int lane = threadIdx.x & 63;
    const int wave = threadIdx.x >> 6;
    const int m = lane & 15;
    const int q = lane >> 4;
    const int row0 = blockIdx.x * 64 + wave * 16;

    int rowa = row0 + m; if (rowa > M - 1) rowa = M - 1;

    constexpr int NT = N / 16;
    f32x4 acc[NT];
    #pragma unroll
    for (int t = 0; t < NT; t++) acc[t] = (f32x4){0.f, 0.f, 0.f, 0.f};

    #pragma unroll
    for (int kc = 0; kc < K; kc += 32) {
        bfrag8 af;
        if constexpr (AF32) {
            const float* ap = (const float*)A_ + (size_t)rowa * K + q * 8 + kc;
            const float4 x0 = *(const float4*)(ap);
            const float4 x1 = *(const float4*)(ap + 4);
            af[0] = (short)f2bf(x0.x); af[1] = (short)f2bf(x0.y);
            af[2] = (short)f2bf(x0.z); af[3] = (short)f2bf(x0.w);
            af[4] = (short)f2bf(x1.x); af[5] = (short)f2bf(x1.y);
            af[6] = (short)f2bf(x1.z); af[7] = (short)f2bf(x1.w);
        } else {
            const u16* ap = (const u16*)A_ + (size_t)rowa * K + q * 8 + kc;
            af = *(const bfrag8*)ap;
        }
        const u16* bbase = Wp + ((size_t)(((kc >> 3) + q) * N) + m) * 8;
        #pragma unroll
        for (int t = 0; t < NT; t++) {
            bfrag8 bf_ = *(const bfrag8*)(bbase + t * 128);
            acc[t] = __builtin_amdgcn_mfma_f32_16x16x32_bf16(af, bf_, acc[t], 0, 0, 0);
        }
    }
    #pragma unroll
    for (int r = 0; r < 4; r++) {
        int gr = row0 + q * 4 + r;
        if (gr < M) {
            int dO = deg[gr]; if (dO < 1) dO = 1;
            float s = rsqrtf((float)dO);
            #pragma unroll
            for (int t = 0; t < NT; t++)
                out[(size_t)gr * N + t * 16 + m] = f2bf(acc[t][r] * s);
        }
    }
}

// ---- layer-1 gather: wave per node, masked unroll-16 (always 16 loads in flight) ----
__global__ __launch_bounds__(256) void gather1(const u32* __restrict__ h, const int* __restrict__ row_ptr,
                                               const u32* __restrict__ sorted, const float* __restrict__ b1,
                                               u32* __restrict__ h1out, int nNodes) {
    int lane = threadIdx.x & 63;
    int node = blockIdx.x * 4 + (threadIdx.x >> 6);
    if (node >= nNodes) return;
    int beg = row_ptr[node], end = row_ptr[node + 1];
    float a0 = 0.f, a1 = 0.f;
    for (int e = beg; e < end; e += 16) {
        u32 p[16];
        #pragma unroll
        for (int j = 0; j < 16; j++) {
            int ee = e + j; ee = (ee < end - 1) ? ee : end - 1;   // clamp: dup loads hit L1
            p[j] = h[(size_t)(sorted[ee] & 0xFFFFu) * 64 + lane];
        }
        #pragma unroll
        for (int j = 0; j < 16; j++)
            if (e + j < end) { a0 += bflo(p[j]); a1 += bfhi(p[j]); }
    }
    int dI = end - beg; if (dI < 1) dI = 1;
    float r = rsqrtf((float)dI);
    float v0 = fmaxf(a0 * r + b1[2 * lane + 0], 0.f);
    float v1 = fmaxf(a1 * r + b1[2 * lane + 1], 0.f);
    h1out[(size_t)node * 64 + lane] = ((u32)f2bf(v1) << 16) | f2bf(v0);
}

// ---- layer-2 gather + projection: half-wave per node, masked unroll-16 ----
__global__ __launch_bounds__(256) void gather2(const u32* __restrict__ h2, const int* __restrict__ row_ptr,
                                               const u32* __restrict__ sorted, const float* __restrict__ b2,
                                               const float* __restrict__ Wf, const float* __restrict__ bfv,
                                               float* __restrict__ logits, float* __restrict__ hidden, int nNodes) {
    int lane = threadIdx.x & 63;
    int l = lane & 31;
    int node = blockIdx.x * 8 + (threadIdx.x >> 5);
    if (node >= nNodes) return;
    int beg = row_ptr[node], end = row_ptr[node + 1];
    float a0 = 0.f, a1 = 0.f;
    for (int e = beg; e < end; e += 16) {
        u32 p[16];
        #pragma unroll
        for (int j = 0; j < 16; j++) {
            int ee = e + j; ee = (ee < end - 1) ? ee : end - 1;
            p[j] = h2[(size_t)(sorted[ee] & 0xFFFFu) * 32 + l];
        }
        #pragma unroll
        for (int j = 0; j < 16; j++)
            if (e + j < end) { a0 += bflo(p[j]); a1 += bfhi(p[j]); }
    }
    int dI = end - beg; if (dI < 1) dI = 1;
    float r = rsqrtf((float)dI);
    float v0 = a0 * r + b2[2 * l + 0];
    float v1 = a1 * r + b2[2 * l + 1];
    hidden[(size_t)node * 64 + 2 * l + 0] = v0;
    hidden[(size_t)node * 64 + 2 * l + 1] = v1;
    float l0 = v0 * Wf[(2 * l) * 2 + 0] + v1 * Wf[(2 * l + 1) * 2 + 0];
    float l1 = v0 * Wf[(2 * l) * 2 + 1] + v1 * Wf[(2 * l + 1) * 2 + 1];
    #pragma unroll
    for (int off = 16; off > 0; off >>= 1) {
        l0 += __shfl_down(l0, off, 32);
        l1 += __shfl_down(l1, off, 32);
    }
    if (l == 0) {
        logits[(size_t)node * 2 + 0] = l0 + bfv[0];
        logits[(size_t)node * 2 + 1] = l1 + bfv[1];
    }
}

extern "C" void kernel_launch(void* const* d_in, const int* in_sizes, int n_in,
                              void* d_out, int out_size, void* d_ws, size_t ws_size,
                              hipStream_t stream) {
    const float* x   = (const float*)d_in[0];
    const float* W1  = (const float*)d_in[1];
    const float* b1  = (const float*)d_in[2];
    const float* W2  = (const float*)d_in[3];
    const float* b2  = (const float*)d_in[4];
    const float* Wf  = (const float*)d_in[5];
    const float* bfv = (const float*)d_in[6];
    const int* src = (const int*)d_in[7];
    const int* dst = (const int*)d_in[8];

    float* out_logits = (float*)d_out;
    float* out_hidden = (float*)d_out + 2 * NNODES;

    char* ws = (char*)d_ws;
    size_t off = 0;
    auto alloc = [&](size_t bytes) { void* p = ws + off; off += (bytes + 255) & ~(size_t)255; return p; };
    u32*   gh1     = (u32*)alloc(GH1TOT * 4);
    u32*   gh2     = (u32*)alloc(GH2TOT * 4);
    int*   scanned = (int*)alloc(GH2TOT * 4);
    int*   partials= (int*)alloc(1024 * 4);
    u32*   sbuf    = (u32*)alloc((size_t)NEDGES * 4);
    u32*   sorted  = (u32*)alloc((size_t)NEDGES * 4);
    u32*   histg   = (u32*)alloc((size_t)DHB * (NNODES / 2) * 4);   // 10 MB
    int*   deg_out = (int*)alloc(NNODES * 4);
    int*   row_ptr = (int*)alloc((NNODES + 1) * 4);
    u16*   Wp1     = (u16*)alloc(256 * 128 * 2);
    u16*   Wp2     = (u16*)alloc(128 * 64 * 2);
    u16*   h       = (u16*)alloc((size_t)NNODES * 128 * 2);
    u16*   h1      = (u16*)alloc((size_t)NNODES * 128 * 2);
    u16*   h2      = (u16*)alloc((size_t)NNODES * 64 * 2);

    // 1: weight prep + degree histogram + pass-1 histogram
    pre_kernel<<<DHB + GA1 + 128, 256, 0, stream>>>(W1, W2, Wp1, Wp2, src, dst, histg, gh1, NEDGES);
    // 2: degree reduce + scan(gh1)
    red_scan1<<<GA1, 256, 0, stream>>>((const u16*)histg, deg_out, gh1, scanned, partials);
    // 3: pass-1 scatter (inline offs)
    scatter1<<<GA1, 256, 0, stream>>>(dst, src, gh1, scanned, partials, sbuf, NEDGES);
    // 4: pass-2 histogram
    hist2<<<SCB / 4, 256, 0, stream>>>(sbuf, gh2, NEDGES);
    // 5: scan(gh2)
    scan2<<<GH2TOT / 256, 256, 0, stream>>>(gh2, scanned, partials);
    // 6: pass-2 stable scatter (inline offs)
    scatter2_stable<<<SCB / 4, 256, 0, stream>>>(sbuf, gh2, scanned, partials, sorted, NEDGES);
    // 7: row pointers
    bounds_kernel<<<NBE, 256, 0, stream>>>(sorted, row_ptr, NEDGES);
    // 8-11: dense pipeline
    gemm_scaled<256, 128, true><<<(NNODES + 63) / 64, 256, 0, stream>>>(x, Wp1, deg_out, h, NNODES);
    gather1<<<(NNODES + 3) / 4, 256, 0, stream>>>((const u32*)h, row_ptr, sorted, b1, (u32*)h1, NNODES);
    gemm_scaled<128, 64, false><<<(NNODES + 63) / 64, 256, 0, stream>>>(h1, Wp2, deg_out, h2, NNODES);
    gather2<<<(NNODES + 7) / 8, 256, 0, stream>>>((const u32*)h2, row_ptr, sorted, b2, Wf, bfv,
                                                  out_logits, out_hidden, NNODES);
}

// Round 11
// 234.328 us; speedup vs baseline: 3.2536x; 1.0512x over previous
//
#include <hip/hip_runtime.h>
#include <hip/hip_bf16.h>
#include <cstdint>
#include <cstddef>

#define NNODES 50000
#define NEDGES 800000
// degree histogram
#define DHB    64
#define DHC    12500                       // 64*12500 = 800000 exact
// sort pass 1 (low byte, unstable OK)
#define CHUNK1 4096
#define GA1    196                         // ceil(NEDGES/CHUNK1)
#define GH1TOT (256 * GA1)                 // 50176
// sort pass 2 (high byte, STABLE): 1 wave per 1000-element chunk
#define C2     1000
#define SCB    800                         // 800*1000 = 800000 exact
#define GH2TOT (256 * SCB)                 // 204800
#define NBE    ((NEDGES + 255) / 256)      // 3125

typedef unsigned short u16;
typedef unsigned int u32;
typedef short bfrag8 __attribute__((ext_vector_type(8)));
typedef float f32x4 __attribute__((ext_vector_type(4)));

__device__ __forceinline__ u16 f2bf(float f) {
    union { float f; uint32_t i; } v; v.f = f;
    uint32_t r = (v.i + 0x7FFFu + ((v.i >> 16) & 1u)) >> 16;
    return (u16)r;
}
__device__ __forceinline__ float bflo(u32 p) { union { uint32_t i; float f; } v; v.i = p << 16; return v.f; }
__device__ __forceinline__ float bfhi(u32 p) { union { uint32_t i; float f; } v; v.i = p & 0xFFFF0000u; return v.f; }

// ============ launch 1: prep_w + deg_hist + hist1 (independent jobs, blockIdx-ranged) ============
__global__ __launch_bounds__(256) void pre_kernel(const float* __restrict__ W1, const float* __restrict__ W2,
                                                  u16* __restrict__ P1, u16* __restrict__ P2,
                                                  const int* __restrict__ src, const int* __restrict__ dst,
                                                  u32* __restrict__ histg, u32* __restrict__ gh1, int nE) {
    __shared__ u32 hh[NNODES / 2];         // 100 KB
    int b = blockIdx.x;
    if (b < DHB) {
        // out-degree histogram: u16 counters packed in u32; per-block count <= 12500 < 65536
        for (int j = threadIdx.x; j < NNODES / 2; j += 256) hh[j] = 0;
        __syncthreads();
        int beg = b * DHC, end = min(beg + DHC, nE);
        for (int i = beg + threadIdx.x; i < end; i += 256) {
            u32 n = (u32)src[i];
            atomicAdd(&hh[n >> 1], 1u << ((n & 1) * 16));
        }
        __syncthreads();
        u32* out = histg + (size_t)b * (NNODES / 2);
        for (int j = threadIdx.x; j < NNODES / 2; j += 256) out[j] = hh[j];
    } else if (b < DHB + GA1) {
        // sort pass-1 histogram (low byte of dst)
        int bb = b - DHB;
        hh[threadIdx.x] = 0;
        __syncthreads();
        int beg = bb * CHUNK1, end = min(beg + CHUNK1, nE);
        for (int i = beg + threadIdx.x; i < end; i += 256)
            atomicAdd(&hh[(u32)dst[i] & 255u], 1);
        __syncthreads();
        gh1[threadIdx.x * GA1 + bb] = hh[threadIdx.x];
    } else {
        // weight prep: fp32 row-major -> bf16 packed B-fragment layout Wpack[k/8][n][k%8]
        int i = (b - DHB - GA1) * 256 + threadIdx.x;
        if (i < 256 * 128) {
            int k = i >> 7, n = i & 127;
            P1[((((k >> 3) << 7) + n) << 3) | (k & 7)] = f2bf(W1[i]);
        }
        if (i < 128 * 64) {
            int k = i >> 6, n = i & 63;
            P2[((((k >> 3) << 6) + n) << 3) | (k & 7)] = f2bf(W2[i]);
        }
    }
}

// ============ launch 2: deg_reduce + per-block inclusive scan of gh1 (grid = 196) ============
__global__ __launch_bounds__(256) void red_scan1(const u16* __restrict__ histg16, int* __restrict__ deg,
                                                 const u32* __restrict__ gh1, int* __restrict__ scanned,
                                                 int* __restrict__ partials) {
    int i = blockIdx.x * 256 + threadIdx.x;
    if (i < NNODES) {
        int s = 0;
        #pragma unroll 4
        for (int b = 0; b < DHB; b++) s += histg16[(size_t)b * NNODES + i];
        deg[i] = s;
    }
    __shared__ int sd[256];
    int t = threadIdx.x;
    int gi = blockIdx.x * 256 + t;          // grid 196 -> gi < 50176 = GH1TOT
    int v = (int)gh1[gi];
    sd[t] = v;
    __syncthreads();
    #pragma unroll
    for (int o = 1; o < 256; o <<= 1) {
        int add = (t >= o) ? sd[t - o] : 0;
        __syncthreads();
        sd[t] += add;
        __syncthreads();
    }
    scanned[gi] = sd[t];
    if (t == 255) partials[blockIdx.x] = sd[255];
}

// ============ launch 3: pass-1 scatter, exclusive base inline (re-scans 196 partials) ============
__global__ __launch_bounds__(256) void scatter1(const int* __restrict__ dst, const int* __restrict__ src,
                                                const u32* __restrict__ gh1, const int* __restrict__ scanned,
                                                const int* __restrict__ partials, u32* __restrict__ sbuf, int nE) {
    __shared__ int sd[256];
    __shared__ int offs_l[256];
    __shared__ u32 base[256];
    __shared__ u32 lh[256];
    int t = threadIdx.x;
    int v = (t < GA1) ? partials[t] : 0;
    sd[t] = v;
    __syncthreads();
    #pragma unroll
    for (int o = 1; o < 256; o <<= 1) {
        int add = (t >= o) ? sd[t - o] : 0;
        __syncthreads();
        sd[t] += add;
        __syncthreads();
    }
    offs_l[t] = sd[t] - v;
    __syncthreads();
    int idx = t * GA1 + blockIdx.x;
    base[t] = (u32)(scanned[idx] + offs_l[idx >> 8] - (int)gh1[idx]);
    lh[t] = 0;
    __syncthreads();
    int beg = blockIdx.x * CHUNK1, end = min(beg + CHUNK1, nE);
    for (int i = beg + t; i < end; i += 256) {
        u32 el = ((u32)dst[i] << 16) | (u32)src[i];
        u32 d = (el >> 16) & 255u;
        u32 r = atomicAdd(&lh[d], 1);
        sbuf[base[d] + r] = el;
    }
}

// ============ launch 4: pass-2 histogram (wave-private, 4 chunks/block) ============
__global__ __launch_bounds__(256) void hist2(const u32* __restrict__ sbuf, u32* __restrict__ gh2, int nE) {
    __shared__ u32 hist[4][256];
    int wave = threadIdx.x >> 6, lane = threadIdx.x & 63;
    int cg = blockIdx.x * 4 + wave;
    for (int j = lane; j < 256; j += 64) hist[wave][j] = 0;
    __syncthreads();
    int beg = cg * C2, end = min(beg + C2, nE);
    for (int i = beg + lane; i < end; i += 64)
        atomicAdd(&hist[wave][sbuf[i] >> 24], 1);
    __syncthreads();
    for (int j = lane; j < 256; j += 64)
        gh2[j * SCB + cg] = hist[wave][j];
}

// ============ launch 5: per-block inclusive scan of gh2 (grid = 800) ============
__global__ __launch_bounds__(256) void scan2(const u32* __restrict__ gh2, int* __restrict__ scanned,
                                             int* __restrict__ partials) {
    __shared__ int sd[256];
    int t = threadIdx.x;
    int gi = blockIdx.x * 256 + t;
    int v = (int)gh2[gi];
    sd[t] = v;
    __syncthreads();
    #pragma unroll
    for (int o = 1; o < 256; o <<= 1) {
        int add = (t >= o) ? sd[t - o] : 0;
        __syncthreads();
        sd[t] += add;
        __syncthreads();
    }
    scanned[gi] = sd[t];
    if (t == 255) partials[blockIdx.x] = sd[255];
}

// ============ launch 6: pass-2 STABLE scatter, base inline (re-scans 800 partials) ============
__global__ __launch_bounds__(256) void scatter2_stable(const u32* __restrict__ sbuf, const u32* __restrict__ gh2,
                                                       const int* __restrict__ scanned, const int* __restrict__ partials,
                                                       u32* __restrict__ sorted, int nE) {
    __shared__ int sd[256];
    __shared__ int offs_l[800];
    __shared__ u32 run[4][256];
    int t = threadIdx.x;
    int v[4]; int s = 0;
    #pragma unroll
    for (int j = 0; j < 4; j++) { int idx = t * 4 + j; v[j] = (idx < 800) ? partials[idx] : 0; s += v[j]; }
    sd[t] = s;
    __syncthreads();
    #pragma unroll
    for (int o = 1; o < 256; o <<= 1) {
        int add = (t >= o) ? sd[t - o] : 0;
        __syncthreads();
        sd[t] += add;
        __syncthreads();
    }
    int bse = sd[t] - s;
    #pragma unroll
    for (int j = 0; j < 4; j++) { int idx = t * 4 + j; if (idx < 800) offs_l[idx] = bse; bse += v[j]; }
    __syncthreads();
    int wave = t >> 6, lane = t & 63;
    int cg = blockIdx.x * 4 + wave;
    for (int j = lane; j < 256; j += 64) {
        int idx = j * SCB + cg;
        run[wave][j] = (u32)(scanned[idx] + offs_l[idx >> 8] - (int)gh2[idx]);
    }
    __syncthreads();
    int beg = cg * C2, end = min(beg + C2, nE);
    for (int i0 = beg; i0 < end; i0 += 64) {
        int i = i0 + lane;
        int active = (i < end);
        u32 el = active ? sbuf[i] : 0;
        u32 d = el >> 24;
        unsigned long long m = __ballot(active);
        #pragma unroll
        for (int b = 0; b < 8; b++) {
            unsigned long long bb_ = __ballot(active && ((d >> b) & 1));
            m &= ((d >> b) & 1) ? bb_ : ~bb_;
        }
        if (active) {
            int lanerank = __popcll(m & ((1ull << lane) - 1ull));
            int leader = __ffsll((long long)m) - 1;
            u32 base = 0;
            if (lane == leader) base = atomicAdd(&run[wave][d], (u32)__popcll(m));
            base = (u32)__shfl((int)base, leader, 64);
            sorted[base + (u32)lanerank] = el;
        }
    }
}

// ============ launch 7: boundary detection -> row_ptr ============
__global__ __launch_bounds__(256) void bounds_kernel(const u32* __restrict__ sorted, int* __restrict__ rp, int nE) {
    int e = blockIdx.x * 256 + threadIdx.x;
    if (e >= nE) return;
    int k = (int)(sorted[e] >> 16);
    int kp = e ? (int)(sorted[e - 1] >> 16) : -1;
    if (k != kp)
        for (int n = kp + 1; n <= k; n++) rp[n] = e;
    if (e == nE - 1)
        for (int n = k + 1; n <= NNODES; n++) rp[n] = nE;
}

// ============ dense compute ============

template <int K, int N, bool AF32>
__global__ __launch_bounds__(256) void gemm_scaled(const void* __restrict__ A_, const u16* __restrict__ Wp,
                                                   const int* __restrict__ deg, u16* __restrict__ out, int M) {
    const int lane = threadIdx.x & 63;
    const int wave = threadIdx.x >> 6;
    const int m = lane & 15;
    const int q = lane >> 4;
    const int row0 = blockIdx.x * 64 + wave * 16;

    int rowa = row0 + m; if (rowa > M - 1) rowa = M - 1;

    constexpr int NT = N / 16;
    f32x4 acc[NT];
    #pragma unroll
    for (int t = 0; t < NT; t++) acc[t] = (f32x4){0.f, 0.f, 0.f, 0.f};

    #pragma unroll
    for (int kc = 0; kc < K; kc += 32) {
        bfrag8 af;
        if constexpr (AF32) {
            const float* ap = (const float*)A_ + (size_t)rowa * K + q * 8 + kc;
            const float4 x0 = *(const float4*)(ap);
            const float4 x1 = *(const float4*)(ap + 4);
            af[0] = (short)f2bf(x0.x); af[1] = (short)f2bf(x0.y);
            af[2] = (short)f2bf(x0.z); af[3] = (short)f2bf(x0.w);
            af[4] = (short)f2bf(x1.x); af[5] = (short)f2bf(x1.y);
            af[6] = (short)f2bf(x1.z); af[7] = (short)f2bf(x1.w);
        } else {
            const u16* ap = (const u16*)A_ + (size_t)rowa * K + q * 8 + kc;
            af = *(const bfrag8*)ap;
        }
        const u16* bbase = Wp + ((size_t)(((kc >> 3) + q) * N) + m) * 8;
        #pragma unroll
        for (int t = 0; t < NT; t++) {
            bfrag8 bf_ = *(const bfrag8*)(bbase + t * 128);
            acc[t] = __builtin_amdgcn_mfma_f32_16x16x32_bf16(af, bf_, acc[t], 0, 0, 0);
        }
    }
    #pragma unroll
    for (int r = 0; r < 4; r++) {
        int gr = row0 + q * 4 + r;
        if (gr < M) {
            int dO = deg[gr]; if (dO < 1) dO = 1;
            float s = rsqrtf((float)dO);
            #pragma unroll
            for (int t = 0; t < NT; t++)
                out[(size_t)gr * N + t * 16 + m] = f2bf(acc[t][r] * s);
        }
    }
}

// ---- layer-1 gather: QUARTER-wave (16 lanes x 16B) per node; unroll-4 rows in flight ----
__global__ __launch_bounds__(256) void gather1(const uint4* __restrict__ h,     // [NNODES][16] uint4
                                               const int* __restrict__ row_ptr,
                                               const u32* __restrict__ sorted, const float* __restrict__ b1,
                                               uint4* __restrict__ h1out, int nNodes) {
    int node = (blockIdx.x * 256 + threadIdx.x) >> 4;    // 16 nodes/block
    int l = threadIdx.x & 15;
    if (node >= nNodes) return;
    int beg = row_ptr[node], end = row_ptr[node + 1];
    float a[8] = {0.f, 0.f, 0.f, 0.f, 0.f, 0.f, 0.f, 0.f};
    for (int e = beg; e < end; e += 4) {
        uint4 p[4];
        #pragma unroll
        for (int j = 0; j < 4; j++) {
            int ee = e + j; ee = (ee < end - 1) ? ee : end - 1;   // clamp: dup loads hit cache
            p[j] = h[(size_t)(sorted[ee] & 0xFFFFu) * 16 + l];
        }
        #pragma unroll
        for (int j = 0; j < 4; j++)
            if (e + j < end) {
                a[0] += bflo(p[j].x); a[1] += bfhi(p[j].x);
                a[2] += bflo(p[j].y); a[3] += bfhi(p[j].y);
                a[4] += bflo(p[j].z); a[5] += bfhi(p[j].z);
                a[6] += bflo(p[j].w); a[7] += bfhi(p[j].w);
            }
    }
    int dI = end - beg; if (dI < 1) dI = 1;
    float r = rsqrtf((float)dI);
    const float4 bA = *(const float4*)(b1 + 8 * l);
    const float4 bB = *(const float4*)(b1 + 8 * l + 4);
    float v0 = fmaxf(a[0] * r + bA.x, 0.f), v1 = fmaxf(a[1] * r + bA.y, 0.f);
    float v2 = fmaxf(a[2] * r + bA.z, 0.f), v3 = fmaxf(a[3] * r + bA.w, 0.f);
    float v4 = fmaxf(a[4] * r + bB.x, 0.f), v5 = fmaxf(a[5] * r + bB.y, 0.f);
    float v6 = fmaxf(a[6] * r + bB.z, 0.f), v7 = fmaxf(a[7] * r + bB.w, 0.f);
    uint4 o;
    o.x = ((u32)f2bf(v1) << 16) | f2bf(v0);
    o.y = ((u32)f2bf(v3) << 16) | f2bf(v2);
    o.z = ((u32)f2bf(v5) << 16) | f2bf(v4);
    o.w = ((u32)f2bf(v7) << 16) | f2bf(v6);
    h1out[(size_t)node * 16 + l] = o;
}

// ---- layer-2 gather + projection: EIGHTH-wave (8 lanes x 16B) per node; unroll-4 ----
__global__ __launch_bounds__(256) void gather2(const uint4* __restrict__ h2,    // [NNODES][8] uint4
                                               const int* __restrict__ row_ptr,
                                               const u32* __restrict__ sorted, const float* __restrict__ b2,
                                               const float* __restrict__ Wf, const float* __restrict__ bfv,
                                               float* __restrict__ logits, float* __restrict__ hidden, int nNodes) {
    int node = (blockIdx.x * 256 + threadIdx.x) >> 3;    // 32 nodes/block
    int l = threadIdx.x & 7;
    if (node >= nNodes) return;
    int beg = row_ptr[node], end = row_ptr[node + 1];
    float a[8] = {0.f, 0.f, 0.f, 0.f, 0.f, 0.f, 0.f, 0.f};
    for (int e = beg; e < end; e += 4) {
        uint4 p[4];
        #pragma unroll
        for (int j = 0; j < 4; j++) {
            int ee = e + j; ee = (ee < end - 1) ? ee : end - 1;
            p[j] = h2[(size_t)(sorted[ee] & 0xFFFFu) * 8 + l];
        }
        #pragma unroll
        for (int j = 0; j < 4; j++)
            if (e + j < end) {
                a[0] += bflo(p[j].x); a[1] += bfhi(p[j].x);
                a[2] += bflo(p[j].y); a[3] += bfhi(p[j].y);
                a[4] += bflo(p[j].z); a[5] += bfhi(p[j].z);
                a[6] += bflo(p[j].w); a[7] += bfhi(p[j].w);
            }
    }
    int dI = end - beg; if (dI < 1) dI = 1;
    float r = rsqrtf((float)dI);
    float v[8];
    #pragma unroll
    for (int f = 0; f < 8; f++) v[f] = a[f] * r + b2[8 * l + f];
    float4 oA = {v[0], v[1], v[2], v[3]};
    float4 oB = {v[4], v[5], v[6], v[7]};
    ((float4*)hidden)[(size_t)node * 16 + 2 * l + 0] = oA;
    ((float4*)hidden)[(size_t)node * 16 + 2 * l + 1] = oB;
    float l0 = 0.f, l1 = 0.f;
    #pragma unroll
    for (int f = 0; f < 8; f++) {
        l0 += v[f] * Wf[(8 * l + f) * 2 + 0];
        l1 += v[f] * Wf[(8 * l + f) * 2 + 1];
    }
    #pragma unroll
    for (int off = 4; off > 0; off >>= 1) {
        l0 += __shfl_down(l0, off, 8);
        l1 += __shfl_down(l1, off, 8);
    }
    if (l == 0) {
        logits[(size_t)node * 2 + 0] = l0 + bfv[0];
        logits[(size_t)node * 2 + 1] = l1 + bfv[1];
    }
}

extern "C" void kernel_launch(void* const* d_in, const int* in_sizes, int n_in,
                              void* d_out, int out_size, void* d_ws, size_t ws_size,
                              hipStream_t stream) {
    const float* x   = (const float*)d_in[0];
    const float* W1  = (const float*)d_in[1];
    const float* b1  = (const float*)d_in[2];
    const float* W2  = (const float*)d_in[3];
    const float* b2  = (const float*)d_in[4];
    const float* Wf  = (const float*)d_in[5];
    const float* bfv = (const float*)d_in[6];
    const int* src = (const int*)d_in[7];
    const int* dst = (const int*)d_in[8];

    float* out_logits = (float*)d_out;
    float* out_hidden = (float*)d_out + 2 * NNODES;

    char* ws = (char*)d_ws;
    size_t off = 0;
    auto alloc = [&](size_t bytes) { void* p = ws + off; off += (bytes + 255) & ~(size_t)255; return p; };
    u32*   gh1     = (u32*)alloc(GH1TOT * 4);
    u32*   gh2     = (u32*)alloc(GH2TOT * 4);
    int*   scanned = (int*)alloc(GH2TOT * 4);
    int*   partials= (int*)alloc(1024 * 4);
    u32*   sbuf    = (u32*)alloc((size_t)NEDGES * 4);
    u32*   sorted  = (u32*)alloc((size_t)NEDGES * 4);
    u32*   histg   = (u32*)alloc((size_t)DHB * (NNODES / 2) * 4);   // 6.4 MB
    int*   deg_out = (int*)alloc(NNODES * 4);
    int*   row_ptr = (int*)alloc((NNODES + 1) * 4);
    u16*   Wp1     = (u16*)alloc(256 * 128 * 2);
    u16*   Wp2     = (u16*)alloc(128 * 64 * 2);
    u16*   h       = (u16*)alloc((size_t)NNODES * 128 * 2);
    u16*   h1      = (u16*)alloc((size_t)NNODES * 128 * 2);
    u16*   h2      = (u16*)alloc((size_t)NNODES * 64 * 2);

    // 1: weight prep + degree histogram + pass-1 histogram
    pre_kernel<<<DHB + GA1 + 128, 256, 0, stream>>>(W1, W2, Wp1, Wp2, src, dst, histg, gh1, NEDGES);
    // 2: degree reduce + scan(gh1)
    red_scan1<<<GA1, 256, 0, stream>>>((const u16*)histg, deg_out, gh1, scanned, partials);
    // 3: pass-1 scatter (inline offs)
    scatter1<<<GA1, 256, 0, stream>>>(dst, src, gh1, scanned, partials, sbuf, NEDGES);
    // 4: pass-2 histogram
    hist2<<<SCB / 4, 256, 0, stream>>>(sbuf, gh2, NEDGES);
    // 5: scan(gh2)
    scan2<<<GH2TOT / 256, 256, 0, stream>>>(gh2, scanned, partials);
    // 6: pass-2 stable scatter (inline offs)
    scatter2_stable<<<SCB / 4, 256, 0, stream>>>(sbuf, gh2, scanned, partials, sorted, NEDGES);
    // 7: row pointers
    bounds_kernel<<<NBE, 256, 0, stream>>>(sorted, row_ptr, NEDGES);
    // 8-11: dense pipeline
    gemm_scaled<256, 128, true><<<(NNODES + 63) / 64, 256, 0, stream>>>(x, Wp1, deg_out, h, NNODES);
    gather1<<<(NNODES * 16 + 255) / 256, 256, 0, stream>>>((const uint4*)h, row_ptr, sorted, b1,
                                                           (uint4*)h1, NNODES);
    gemm_scaled<128, 64, false><<<(NNODES + 63) / 64, 256, 0, stream>>>(h1, Wp2, deg_out, h2, NNODES);
    gather2<<<(NNODES * 8 + 255) / 256, 256, 0, stream>>>((const uint4*)h2, row_ptr, sorted, b2, Wf, bfv,
                                                          out_logits, out_hidden, NNODES);
}